// Round 1
// baseline (1199.603 us; speedup 1.0000x reference)
//
#include <hip/hip_runtime.h>
#include <hip/hip_bf16.h>
#include <math.h>

#define N_NODES 20000
#define N_EDGES 160000
#define FIN 64
#define EDGE_DIM 8
#define H_HEADS 4
#define C_CH 128
#define HC 512
#define NUM_RELS 4
#define E_TOT (N_EDGES + N_NODES)   // edges + self-loops = 180000

// ---------- helpers ----------
__device__ __forceinline__ unsigned enc_f(float f) {
    unsigned u = __float_as_uint(f);
    return (u & 0x80000000u) ? ~u : (u | 0x80000000u);
}
__device__ __forceinline__ float dec_f(unsigned k) {
    return (k & 0x80000000u) ? __uint_as_float(k ^ 0x80000000u) : __uint_as_float(~k);
}

// ---------- fp32 tiled GEMM: C[M,N] = A[M,K] @ B[K,N] ----------
// 64x64 tile, BK=16, 256 threads, 4x4 per thread. N,K multiples of 16/64; M guarded.
__global__ __launch_bounds__(256)
void k_gemm(const float* __restrict__ A, const float* __restrict__ B,
            float* __restrict__ C, int M, int K, int N) {
    __shared__ float As[16][65];
    __shared__ float Bs[16][65];
    const int t = threadIdx.x;
    const int tx = t & 15, ty = t >> 4;
    const int br = blockIdx.y * 64, bc = blockIdx.x * 64;
    float acc[4][4] = {};
    for (int k0 = 0; k0 < K; k0 += 16) {
        #pragma unroll
        for (int i = 0; i < 4; ++i) {
            int idx = t + i * 256;
            int r = idx >> 4, kk = idx & 15;
            int gr = br + r;
            As[kk][r] = (gr < M) ? A[(size_t)gr * K + k0 + kk] : 0.f;
        }
        #pragma unroll
        for (int i = 0; i < 4; ++i) {
            int idx = t + i * 256;
            int kk = idx >> 6, c = idx & 63;
            Bs[kk][c] = B[(size_t)(k0 + kk) * N + bc + c];
        }
        __syncthreads();
        #pragma unroll
        for (int kk = 0; kk < 16; ++kk) {
            float a[4], b[4];
            #pragma unroll
            for (int j = 0; j < 4; ++j) a[j] = As[kk][ty * 4 + j];
            #pragma unroll
            for (int j = 0; j < 4; ++j) b[j] = Bs[kk][tx * 4 + j];
            #pragma unroll
            for (int j = 0; j < 4; ++j)
                #pragma unroll
                for (int l = 0; l < 4; ++l) acc[j][l] += a[j] * b[l];
        }
        __syncthreads();
    }
    #pragma unroll
    for (int j = 0; j < 4; ++j) {
        int gr = br + ty * 4 + j;
        if (gr < M) {
            #pragma unroll
            for (int l = 0; l < 4; ++l)
                C[(size_t)gr * N + bc + tx * 4 + l] = acc[j][l];
        }
    }
}

// ---------- self-loop mean edge features ----------
__global__ void k_mean_acc(const int* __restrict__ ei, const float* __restrict__ ef,
                           float* __restrict__ fsum, float* __restrict__ cnt) {
    int e = blockIdx.x * 256 + threadIdx.x;
    if (e >= N_EDGES) return;
    int dst = ei[N_EDGES + e];
    #pragma unroll
    for (int d = 0; d < 8; ++d) atomicAdd(fsum + dst * 8 + d, ef[(size_t)e * 8 + d]);
    atomicAdd(cnt + dst, 1.f);
}
__global__ void k_mean_div(float* __restrict__ fsum, const float* __restrict__ cnt) {
    int i = blockIdx.x * 256 + threadIdx.x;
    if (i >= N_NODES * 8) return;
    fsum[i] = fsum[i] / fmaxf(cnt[i >> 3], 1.f);
}

// ---------- q[h][d] = sum_c We[d, h*128+c] * a_e[h,c]  (both layers) ----------
__global__ void k_prep_q(const float* __restrict__ We1, const float* __restrict__ ae1,
                         const float* __restrict__ We2, const float* __restrict__ ae2,
                         float* __restrict__ q1, float* __restrict__ q2) {
    int t = threadIdx.x;
    if (t >= 64) return;
    const float* We = (t < 32) ? We1 : We2;
    const float* ae = (t < 32) ? ae1 : ae2;
    float* q = (t < 32) ? q1 : q2;
    int i = t & 31, h = i >> 3, d = i & 7;
    float s = 0.f;
    for (int c = 0; c < 128; ++c) s += We[d * 512 + h * 128 + c] * ae[h * 128 + c];
    q[i] = s;
}

// ---------- collapsed decoder weights: M = Wd1@Wd2 (1024x4), c = bd1@Wd2+bd2 ----------
__global__ void k_prep_M(const float* __restrict__ Wd1, const float* __restrict__ Wd2,
                         const float* __restrict__ bd1, const float* __restrict__ bd2,
                         float* __restrict__ M, float* __restrict__ cvec) {
    int tid = blockIdx.x * 256 + threadIdx.x;   // 4096 total
    int i = tid >> 2, r = tid & 3;
    float s = 0.f;
    for (int k = 0; k < 256; ++k) s += Wd1[i * 256 + k] * Wd2[k * 4 + r];
    M[tid] = s;
    if (tid < 4) {
        float c = 0.f;
        for (int k = 0; k < 256; ++k) c += bd1[k] * Wd2[k * 4 + tid];
        cvec[tid] = c + bd2[tid];
    }
}

// ---------- per-node alpha_src / alpha_dst: one wave per node ----------
__global__ __launch_bounds__(256)
void k_node_alpha(const float* __restrict__ xp, const float* __restrict__ a_s,
                  const float* __restrict__ a_d, float* __restrict__ as_out,
                  float* __restrict__ ad_out) {
    int n = blockIdx.x * 4 + (threadIdx.x >> 6);
    int lane = threadIdx.x & 63;
    if (n >= N_NODES) return;
    int h = lane >> 4;
    const float* xpp = xp + (size_t)n * HC + lane * 8;
    float4 v0 = *(const float4*)xpp;
    float4 v1 = *(const float4*)(xpp + 4);
    const float* ap = a_s + h * C_CH + (lane & 15) * 8;
    const float* dp = a_d + h * C_CH + (lane & 15) * 8;
    float4 a0 = *(const float4*)ap, a1 = *(const float4*)(ap + 4);
    float4 d0 = *(const float4*)dp, d1 = *(const float4*)(dp + 4);
    float s = v0.x * a0.x + v0.y * a0.y + v0.z * a0.z + v0.w * a0.w +
              v1.x * a1.x + v1.y * a1.y + v1.z * a1.z + v1.w * a1.w;
    float d = v0.x * d0.x + v0.y * d0.y + v0.z * d0.z + v0.w * d0.w +
              v1.x * d1.x + v1.y * d1.y + v1.z * d1.z + v1.w * d1.w;
    #pragma unroll
    for (int off = 8; off; off >>= 1) {
        s += __shfl_xor(s, off);
        d += __shfl_xor(d, off);
    }
    if ((lane & 15) == 0) {
        as_out[n * 4 + h] = s;
        ad_out[n * 4 + h] = d;
    }
}

// ---------- edge alpha pass 1: leaky_relu(as[src]+ad[dst]+ae), atomicMax per (dst,h) ----------
__global__ void k_edge_alpha1(const int* __restrict__ ei, const float* __restrict__ ef,
                              const float* __restrict__ meanf, const float* __restrict__ q,
                              const float* __restrict__ as, const float* __restrict__ ad,
                              float* __restrict__ alpha, unsigned* __restrict__ m_enc) {
    int e = blockIdx.x * 256 + threadIdx.x;
    if (e >= E_TOT) return;
    int src, dst;
    const float* fe;
    if (e < N_EDGES) { src = ei[e]; dst = ei[N_EDGES + e]; fe = ef + (size_t)e * 8; }
    else             { src = dst = e - N_EDGES; fe = meanf + (size_t)src * 8; }
    float f[8];
    #pragma unroll
    for (int d = 0; d < 8; ++d) f[d] = fe[d];
    #pragma unroll
    for (int h = 0; h < 4; ++h) {
        float ae = 0.f;
        #pragma unroll
        for (int d = 0; d < 8; ++d) ae += f[d] * q[h * 8 + d];
        float a = as[src * 4 + h] + ad[dst * 4 + h] + ae;
        a = (a > 0.f) ? a : 0.2f * a;
        alpha[(size_t)e * 4 + h] = a;
        atomicMax(m_enc + dst * 4 + h, enc_f(a));
    }
}

// ---------- edge alpha pass 2: ex = exp(alpha - m[dst]); den += ex ----------
__global__ void k_edge_alpha2(const int* __restrict__ ei, float* __restrict__ alpha,
                              const unsigned* __restrict__ m_enc, float* __restrict__ den) {
    int e = blockIdx.x * 256 + threadIdx.x;
    if (e >= E_TOT) return;
    int dst = (e < N_EDGES) ? ei[N_EDGES + e] : (e - N_EDGES);
    #pragma unroll
    for (int h = 0; h < 4; ++h) {
        float m = dec_f(m_enc[dst * 4 + h]);
        float ex = expf(alpha[(size_t)e * 4 + h] - m);
        alpha[(size_t)e * 4 + h] = ex;
        atomicAdd(den + dst * 4 + h, ex);
    }
}

// ---------- aggregation: acc[dst] += xp[src] * ex ; one wave per edge ----------
__global__ __launch_bounds__(256)
void k_aggregate(const int* __restrict__ ei, const float* __restrict__ xp,
                 const float* __restrict__ exw, float* __restrict__ acc) {
    int e = blockIdx.x * 4 + (threadIdx.x >> 6);
    int lane = threadIdx.x & 63;
    if (e >= E_TOT) return;
    int src, dst;
    if (e < N_EDGES) { src = ei[e]; dst = ei[N_EDGES + e]; }
    else             { src = dst = e - N_EDGES; }
    float4 w4 = *(const float4*)(exw + (size_t)e * 4);
    float w[4] = {w4.x, w4.y, w4.z, w4.w};
    const float* xs = xp + (size_t)src * HC;
    float* ao = acc + (size_t)dst * HC;
    #pragma unroll
    for (int j = 0; j < 8; ++j) {
        int ch = j * 64 + lane;
        atomicAdd(ao + ch, xs[ch] * w[j >> 1]);
    }
}

// ---------- finalize: z = elu(acc/den + b) in place ----------
__global__ void k_finalize(float* __restrict__ acc, const float* __restrict__ den,
                           const float* __restrict__ b) {
    size_t i = (size_t)blockIdx.x * 256 + threadIdx.x;
    if (i >= (size_t)N_NODES * HC) return;
    int n = (int)(i >> 9), ch = (int)(i & 511), h = ch >> 7;
    float v = acc[i] / den[n * 4 + h] + b[ch];
    acc[i] = (v > 0.f) ? v : expm1f(v);
}

// ---------- decoder: U = z@M_top, V = z@M_bot (one wave per node) ----------
__global__ __launch_bounds__(256)
void k_UV(const float* __restrict__ z, const float* __restrict__ M,
          float* __restrict__ U, float* __restrict__ V) {
    int n = blockIdx.x * 4 + (threadIdx.x >> 6);
    int lane = threadIdx.x & 63;
    if (n >= N_NODES) return;
    const float* zp = z + (size_t)n * HC + lane * 8;
    float4 z0 = *(const float4*)zp, z1 = *(const float4*)(zp + 4);
    float zf[8] = {z0.x, z0.y, z0.z, z0.w, z1.x, z1.y, z1.z, z1.w};
    float u[4] = {}, v[4] = {};
    #pragma unroll
    for (int j = 0; j < 8; ++j) {
        int f = lane * 8 + j;
        #pragma unroll
        for (int r = 0; r < 4; ++r) {
            u[r] += zf[j] * M[f * 4 + r];
            v[r] += zf[j] * M[(512 + f) * 4 + r];
        }
    }
    #pragma unroll
    for (int r = 0; r < 4; ++r) {
        #pragma unroll
        for (int off = 32; off; off >>= 1) {
            u[r] += __shfl_xor(u[r], off);
            v[r] += __shfl_xor(v[r], off);
        }
    }
    if (lane == 0) {
        #pragma unroll
        for (int r = 0; r < 4; ++r) { U[n * 4 + r] = u[r]; V[n * 4 + r] = v[r]; }
    }
}

// ---------- per-edge output: sigmoid(U[src]+V[dst]+c) ----------
__global__ void k_edge_out(const int* __restrict__ ei, const float* __restrict__ U,
                           const float* __restrict__ V, const float* __restrict__ cvec,
                           float* __restrict__ out) {
    int idx = blockIdx.x * 256 + threadIdx.x;
    if (idx >= N_EDGES * 4) return;
    int e = idx >> 2, r = idx & 3;
    float val = U[ei[e] * 4 + r] + V[ei[N_EDGES + e] * 4 + r] + cvec[r];
    out[idx] = 1.f / (1.f + expf(-val));
}

extern "C" void kernel_launch(void* const* d_in, const int* in_sizes, int n_in,
                              void* d_out, int out_size, void* d_ws, size_t ws_size,
                              hipStream_t stream) {
    (void)in_sizes; (void)n_in; (void)out_size; (void)ws_size;
    const float* x      = (const float*)d_in[0];
    const int*   ei     = (const int*)d_in[1];
    const float* ef     = (const float*)d_in[2];
    const float* W1     = (const float*)d_in[3];
    const float* a_src1 = (const float*)d_in[4];
    const float* a_dst1 = (const float*)d_in[5];
    const float* We1    = (const float*)d_in[6];
    const float* a_e1   = (const float*)d_in[7];
    const float* b1     = (const float*)d_in[8];
    const float* W2     = (const float*)d_in[9];
    const float* a_src2 = (const float*)d_in[10];
    const float* a_dst2 = (const float*)d_in[11];
    const float* We2    = (const float*)d_in[12];
    const float* a_e2   = (const float*)d_in[13];
    const float* b2     = (const float*)d_in[14];
    const float* Wd1    = (const float*)d_in[15];
    const float* bd1    = (const float*)d_in[16];
    const float* Wd2    = (const float*)d_in[17];
    const float* bd2    = (const float*)d_in[18];
    float* out = (float*)d_out;

    // workspace layout (floats)
    float* A     = (float*)d_ws;                       // N*512  (xp of current layer)
    float* Bacc  = A + (size_t)N_NODES * HC;           // N*512  (accumulator / z)
    float* alpha = Bacc + (size_t)N_NODES * HC;        // E_TOT*4
    unsigned* m_enc = (unsigned*)(alpha + (size_t)E_TOT * 4); // N*4
    float* den   = (float*)(m_enc + N_NODES * 4);      // N*4
    float* as_   = den + N_NODES * 4;                  // N*4
    float* ad_   = as_ + N_NODES * 4;                  // N*4
    float* meanf = ad_ + N_NODES * 4;                  // N*8
    float* cnt   = meanf + N_NODES * 8;                // N
    float* q1    = cnt + N_NODES;                      // 32
    float* q2    = q1 + 32;                            // 32
    float* Mm    = q2 + 32;                            // 4096
    float* cv    = Mm + 4096;                          // 4
    float* U     = cv + 4;                             // N*4
    float* V     = U + N_NODES * 4;                    // N*4

    // ---- prep ----
    hipMemsetAsync(meanf, 0, (N_NODES * 8 + N_NODES) * sizeof(float), stream); // meanf+cnt
    hipMemsetAsync(m_enc, 0, N_NODES * 4 * sizeof(unsigned) * 2, stream);      // m_enc+den
    hipMemsetAsync(Bacc, 0, (size_t)N_NODES * HC * sizeof(float), stream);
    k_mean_acc<<<(N_EDGES + 255) / 256, 256, 0, stream>>>(ei, ef, meanf, cnt);
    k_mean_div<<<(N_NODES * 8 + 255) / 256, 256, 0, stream>>>(meanf, cnt);
    k_prep_q<<<1, 64, 0, stream>>>(We1, a_e1, We2, a_e2, q1, q2);
    k_prep_M<<<16, 256, 0, stream>>>(Wd1, Wd2, bd1, bd2, Mm, cv);

    // ---- layer 1 ----
    k_gemm<<<dim3(HC / 64, (N_NODES + 63) / 64), 256, 0, stream>>>(x, W1, A, N_NODES, FIN, HC);
    k_node_alpha<<<(N_NODES + 3) / 4, 256, 0, stream>>>(A, a_src1, a_dst1, as_, ad_);
    k_edge_alpha1<<<(E_TOT + 255) / 256, 256, 0, stream>>>(ei, ef, meanf, q1, as_, ad_, alpha, m_enc);
    k_edge_alpha2<<<(E_TOT + 255) / 256, 256, 0, stream>>>(ei, alpha, m_enc, den);
    k_aggregate<<<(E_TOT + 3) / 4, 256, 0, stream>>>(ei, A, alpha, Bacc);
    k_finalize<<<(N_NODES * HC + 255) / 256, 256, 0, stream>>>(Bacc, den, b1);

    // ---- layer 2 ----
    k_gemm<<<dim3(HC / 64, (N_NODES + 63) / 64), 256, 0, stream>>>(Bacc, W2, A, N_NODES, HC, HC);
    k_node_alpha<<<(N_NODES + 3) / 4, 256, 0, stream>>>(A, a_src2, a_dst2, as_, ad_);
    hipMemsetAsync(m_enc, 0, N_NODES * 4 * sizeof(unsigned) * 2, stream);      // m_enc+den
    k_edge_alpha1<<<(E_TOT + 255) / 256, 256, 0, stream>>>(ei, ef, meanf, q2, as_, ad_, alpha, m_enc);
    k_edge_alpha2<<<(E_TOT + 255) / 256, 256, 0, stream>>>(ei, alpha, m_enc, den);
    hipMemsetAsync(Bacc, 0, (size_t)N_NODES * HC * sizeof(float), stream);
    k_aggregate<<<(E_TOT + 3) / 4, 256, 0, stream>>>(ei, A, alpha, Bacc);
    k_finalize<<<(N_NODES * HC + 255) / 256, 256, 0, stream>>>(Bacc, den, b2);

    // ---- decoder (collapsed linear) ----
    k_UV<<<(N_NODES + 3) / 4, 256, 0, stream>>>(Bacc, Mm, U, V);
    k_edge_out<<<(N_EDGES * 4 + 255) / 256, 256, 0, stream>>>(ei, U, V, cv, out);
}

// Round 2
// 595.552 us; speedup vs baseline: 2.0143x; 2.0143x over previous
//
#include <hip/hip_runtime.h>
#include <hip/hip_bf16.h>
#include <math.h>

#define N_NODES 20000
#define N_EDGES 160000
#define FIN 64
#define EDGE_DIM 8
#define H_HEADS 4
#define C_CH 128
#define HC 512
#define NUM_RELS 4
#define E_TOT (N_EDGES + N_NODES)   // edges + self-loops = 180000

// ---------- fp32 tiled GEMM: C[M,N] = A[M,K] @ B[K,N] ----------
__global__ __launch_bounds__(256)
void k_gemm(const float* __restrict__ A, const float* __restrict__ B,
            float* __restrict__ C, int M, int K, int N) {
    __shared__ float As[16][65];
    __shared__ float Bs[16][65];
    const int t = threadIdx.x;
    const int tx = t & 15, ty = t >> 4;
    const int br = blockIdx.y * 64, bc = blockIdx.x * 64;
    float acc[4][4] = {};
    for (int k0 = 0; k0 < K; k0 += 16) {
        #pragma unroll
        for (int i = 0; i < 4; ++i) {
            int idx = t + i * 256;
            int r = idx >> 4, kk = idx & 15;
            int gr = br + r;
            As[kk][r] = (gr < M) ? A[(size_t)gr * K + k0 + kk] : 0.f;
        }
        #pragma unroll
        for (int i = 0; i < 4; ++i) {
            int idx = t + i * 256;
            int kk = idx >> 6, c = idx & 63;
            Bs[kk][c] = B[(size_t)(k0 + kk) * N + bc + c];
        }
        __syncthreads();
        #pragma unroll
        for (int kk = 0; kk < 16; ++kk) {
            float a[4], b[4];
            #pragma unroll
            for (int j = 0; j < 4; ++j) a[j] = As[kk][ty * 4 + j];
            #pragma unroll
            for (int j = 0; j < 4; ++j) b[j] = Bs[kk][tx * 4 + j];
            #pragma unroll
            for (int j = 0; j < 4; ++j)
                #pragma unroll
                for (int l = 0; l < 4; ++l) acc[j][l] += a[j] * b[l];
        }
        __syncthreads();
    }
    #pragma unroll
    for (int j = 0; j < 4; ++j) {
        int gr = br + ty * 4 + j;
        if (gr < M) {
            #pragma unroll
            for (int l = 0; l < 4; ++l)
                C[(size_t)gr * N + bc + tx * 4 + l] = acc[j][l];
        }
    }
}

// ---------- self-loop mean edge features ----------
__global__ void k_mean_acc(const int* __restrict__ ei, const float* __restrict__ ef,
                           float* __restrict__ fsum, float* __restrict__ cnt) {
    int e = blockIdx.x * 256 + threadIdx.x;
    if (e >= N_EDGES) return;
    int dst = ei[N_EDGES + e];
    #pragma unroll
    for (int d = 0; d < 8; ++d) atomicAdd(fsum + dst * 8 + d, ef[(size_t)e * 8 + d]);
    atomicAdd(cnt + dst, 1.f);
}
__global__ void k_mean_div(float* __restrict__ fsum, const float* __restrict__ cnt) {
    int i = blockIdx.x * 256 + threadIdx.x;
    if (i >= N_NODES * 8) return;
    fsum[i] = fsum[i] / fmaxf(cnt[i >> 3], 1.f);
}

// ---------- q[h][d] = sum_c We[d, h*128+c] * a_e[h,c] ----------
__global__ void k_prep_q(const float* __restrict__ We1, const float* __restrict__ ae1,
                         const float* __restrict__ We2, const float* __restrict__ ae2,
                         float* __restrict__ q1, float* __restrict__ q2) {
    int t = threadIdx.x;
    if (t >= 64) return;
    const float* We = (t < 32) ? We1 : We2;
    const float* ae = (t < 32) ? ae1 : ae2;
    float* q = (t < 32) ? q1 : q2;
    int i = t & 31, h = i >> 3, d = i & 7;
    float s = 0.f;
    for (int c = 0; c < 128; ++c) s += We[d * 512 + h * 128 + c] * ae[h * 128 + c];
    q[i] = s;
}

// ---------- collapsed decoder: M = Wd1@Wd2 (1024x4), c = bd1@Wd2+bd2 ----------
__global__ void k_prep_M(const float* __restrict__ Wd1, const float* __restrict__ Wd2,
                         const float* __restrict__ bd1, const float* __restrict__ bd2,
                         float* __restrict__ M, float* __restrict__ cvec) {
    int tid = blockIdx.x * 256 + threadIdx.x;   // 4096 total
    int i = tid >> 2, r = tid & 3;
    float s = 0.f;
    for (int k = 0; k < 256; ++k) s += Wd1[i * 256 + k] * Wd2[k * 4 + r];
    M[tid] = s;
    if (tid < 4) {
        float c = 0.f;
        for (int k = 0; k < 256; ++k) c += bd1[k] * Wd2[k * 4 + tid];
        cvec[tid] = c + bd2[tid];
    }
}

// ---------- CSR build ----------
__global__ void k_count(const int* __restrict__ ei, int* __restrict__ counts) {
    int e = blockIdx.x * 256 + threadIdx.x;
    if (e >= E_TOT) return;
    int dst = (e < N_EDGES) ? ei[N_EDGES + e] : (e - N_EDGES);
    atomicAdd(counts + dst, 1);
}

__global__ __launch_bounds__(1024)
void k_scan(const int* __restrict__ counts, int* __restrict__ row_start,
            int* __restrict__ nxt) {
    __shared__ int part[1024];
    int t = threadIdx.x;
    int base = t * 20;
    int pre[20];
    int s = 0;
    #pragma unroll
    for (int i = 0; i < 20; ++i) {
        int idx = base + i;
        int c = (idx < N_NODES) ? counts[idx] : 0;
        pre[i] = s; s += c;
    }
    part[t] = s;
    __syncthreads();
    for (int off = 1; off < 1024; off <<= 1) {
        int v = (t >= off) ? part[t - off] : 0;
        __syncthreads();
        part[t] += v;
        __syncthreads();
    }
    int excl = (t == 0) ? 0 : part[t - 1];
    #pragma unroll
    for (int i = 0; i < 20; ++i) {
        int idx = base + i;
        if (idx < N_NODES) { int v = excl + pre[i]; row_start[idx] = v; nxt[idx] = v; }
    }
    if (t == 1023) row_start[N_NODES] = part[1023];
}

__global__ void k_scatter(const int* __restrict__ ei, int* __restrict__ nxt,
                          int* __restrict__ csr_src, int* __restrict__ csr_eid) {
    int e = blockIdx.x * 256 + threadIdx.x;
    if (e >= E_TOT) return;
    int src, dst;
    if (e < N_EDGES) { src = ei[e]; dst = ei[N_EDGES + e]; }
    else             { src = dst = e - N_EDGES; }
    int pos = atomicAdd(nxt + dst, 1);
    csr_src[pos] = src;
    csr_eid[pos] = e;
}

// ---------- per-node alpha_src / alpha_dst ----------
__global__ __launch_bounds__(256)
void k_node_alpha(const float* __restrict__ xp, const float* __restrict__ a_s,
                  const float* __restrict__ a_d, float* __restrict__ as_out,
                  float* __restrict__ ad_out) {
    int n = blockIdx.x * 4 + (threadIdx.x >> 6);
    int lane = threadIdx.x & 63;
    if (n >= N_NODES) return;
    int h = lane >> 4;
    const float* xpp = xp + (size_t)n * HC + lane * 8;
    float4 v0 = *(const float4*)xpp;
    float4 v1 = *(const float4*)(xpp + 4);
    const float* ap = a_s + h * C_CH + (lane & 15) * 8;
    const float* dp = a_d + h * C_CH + (lane & 15) * 8;
    float4 a0 = *(const float4*)ap, a1 = *(const float4*)(ap + 4);
    float4 d0 = *(const float4*)dp, d1 = *(const float4*)(dp + 4);
    float s = v0.x * a0.x + v0.y * a0.y + v0.z * a0.z + v0.w * a0.w +
              v1.x * a1.x + v1.y * a1.y + v1.z * a1.z + v1.w * a1.w;
    float d = v0.x * d0.x + v0.y * d0.y + v0.z * d0.z + v0.w * d0.w +
              v1.x * d1.x + v1.y * d1.y + v1.z * d1.z + v1.w * d1.w;
    #pragma unroll
    for (int off = 8; off; off >>= 1) {
        s += __shfl_xor(s, off);
        d += __shfl_xor(d, off);
    }
    if ((lane & 15) == 0) {
        as_out[n * 4 + h] = s;
        ad_out[n * 4 + h] = d;
    }
}

// ---------- alpha_e per edge (incl. self-loops) ----------
__global__ void k_edge_ae(const int* __restrict__ ei, const float* __restrict__ ef,
                          const float* __restrict__ meanf, const float* __restrict__ q,
                          float* __restrict__ ae_all) {
    int e = blockIdx.x * 256 + threadIdx.x;
    if (e >= E_TOT) return;
    const float* fe = (e < N_EDGES) ? (ef + (size_t)e * 8)
                                    : (meanf + (size_t)(e - N_EDGES) * 8);
    float f[8];
    #pragma unroll
    for (int d = 0; d < 8; ++d) f[d] = fe[d];
    float4 o;
    float* op = &o.x;
    #pragma unroll
    for (int h = 0; h < 4; ++h) {
        float s = 0.f;
        #pragma unroll
        for (int d = 0; d < 8; ++d) s += f[d] * q[h * 8 + d];
        op[h] = s;
    }
    *(float4*)(ae_all + (size_t)e * 4) = o;
}

__device__ __forceinline__ void edge_alpha(int src, int eid, const float4 adn,
                                           const float* __restrict__ as_,
                                           const float* __restrict__ ae_all,
                                           float& a0, float& a1, float& a2, float& a3) {
    float4 asv = *(const float4*)(as_ + src * 4);
    float4 aev = *(const float4*)(ae_all + (size_t)eid * 4);
    a0 = asv.x + adn.x + aev.x; a0 = a0 > 0.f ? a0 : 0.2f * a0;
    a1 = asv.y + adn.y + aev.y; a1 = a1 > 0.f ? a1 : 0.2f * a1;
    a2 = asv.z + adn.z + aev.z; a2 = a2 > 0.f ? a2 : 0.2f * a2;
    a3 = asv.w + adn.w + aev.w; a3 = a3 > 0.f ? a3 : 0.2f * a3;
}

// ---------- fused per-dst: softmax + aggregate + ELU (+ decoder UV in layer 2) ----------
template <int LAYER>
__global__ __launch_bounds__(256)
void k_dst_fused(const int* __restrict__ row_start, const int* __restrict__ csr_src,
                 const int* __restrict__ csr_eid, const float* __restrict__ xp,
                 const float* __restrict__ ae_all, const float* __restrict__ as_,
                 const float* __restrict__ ad_, const float* __restrict__ b,
                 float* __restrict__ zout, const float* __restrict__ Mm,
                 float* __restrict__ U, float* __restrict__ V) {
    int n = blockIdx.x * 4 + (threadIdx.x >> 6);
    int lane = threadIdx.x & 63;
    if (n >= N_NODES) return;
    int rs = row_start[n], re = row_start[n + 1];
    float4 adn = *(const float4*)(ad_ + n * 4);
    int hl = lane >> 4;

    // pass A: per-head segment max
    float m0 = -1e30f, m1 = -1e30f, m2 = -1e30f, m3 = -1e30f;
    for (int base = rs; base < re; base += 64) {
        int i = base + lane;
        if (i < re) {
            float a0, a1, a2, a3;
            edge_alpha(csr_src[i], csr_eid[i], adn, as_, ae_all, a0, a1, a2, a3);
            m0 = fmaxf(m0, a0); m1 = fmaxf(m1, a1);
            m2 = fmaxf(m2, a2); m3 = fmaxf(m3, a3);
        }
    }
    #pragma unroll
    for (int off = 32; off; off >>= 1) {
        m0 = fmaxf(m0, __shfl_xor(m0, off));
        m1 = fmaxf(m1, __shfl_xor(m1, off));
        m2 = fmaxf(m2, __shfl_xor(m2, off));
        m3 = fmaxf(m3, __shfl_xor(m3, off));
    }

    // pass B: exp, denominator, weighted aggregation (unnormalized)
    float d0 = 0.f, d1 = 0.f, d2 = 0.f, d3 = 0.f;
    float acc[8] = {};
    for (int base = rs; base < re; base += 64) {
        int i = base + lane;
        float e0 = 0.f, e1 = 0.f, e2 = 0.f, e3 = 0.f;
        int src = 0;
        if (i < re) {
            src = csr_src[i];
            float a0, a1, a2, a3;
            edge_alpha(src, csr_eid[i], adn, as_, ae_all, a0, a1, a2, a3);
            e0 = expf(a0 - m0); e1 = expf(a1 - m1);
            e2 = expf(a2 - m2); e3 = expf(a3 - m3);
            d0 += e0; d1 += e1; d2 += e2; d3 += e3;
        }
        int cn = min(64, re - base);
        for (int j = 0; j < cn; ++j) {
            float w0 = __shfl(e0, j), w1 = __shfl(e1, j);
            float w2 = __shfl(e2, j), w3 = __shfl(e3, j);
            int sj = __shfl(src, j);
            float w = (hl == 0) ? w0 : (hl == 1) ? w1 : (hl == 2) ? w2 : w3;
            const float* xs = xp + (size_t)sj * HC + lane * 8;
            float4 x0 = *(const float4*)xs, x1 = *(const float4*)(xs + 4);
            acc[0] += x0.x * w; acc[1] += x0.y * w; acc[2] += x0.z * w; acc[3] += x0.w * w;
            acc[4] += x1.x * w; acc[5] += x1.y * w; acc[6] += x1.z * w; acc[7] += x1.w * w;
        }
    }
    #pragma unroll
    for (int off = 32; off; off >>= 1) {
        d0 += __shfl_xor(d0, off); d1 += __shfl_xor(d1, off);
        d2 += __shfl_xor(d2, off); d3 += __shfl_xor(d3, off);
    }
    float den = (hl == 0) ? d0 : (hl == 1) ? d1 : (hl == 2) ? d2 : d3;
    float inv = 1.f / den;

    // finalize: z = elu(acc/den + b)
    float z[8];
    const float* bp = b + lane * 8;
    #pragma unroll
    for (int k = 0; k < 8; ++k) {
        float v = acc[k] * inv + bp[k];
        z[k] = (v > 0.f) ? v : expm1f(v);
    }

    if (LAYER == 1) {
        float* zp = zout + (size_t)n * HC + lane * 8;
        *(float4*)zp = make_float4(z[0], z[1], z[2], z[3]);
        *(float4*)(zp + 4) = make_float4(z[4], z[5], z[6], z[7]);
    } else {
        // fused decoder: U = z@M_top, V = z@M_bot
        float u[4] = {}, v[4] = {};
        #pragma unroll
        for (int k = 0; k < 8; ++k) {
            int f = lane * 8 + k;
            #pragma unroll
            for (int r = 0; r < 4; ++r) {
                u[r] += z[k] * Mm[f * 4 + r];
                v[r] += z[k] * Mm[(512 + f) * 4 + r];
            }
        }
        #pragma unroll
        for (int r = 0; r < 4; ++r) {
            #pragma unroll
            for (int off = 32; off; off >>= 1) {
                u[r] += __shfl_xor(u[r], off);
                v[r] += __shfl_xor(v[r], off);
            }
        }
        if (lane == 0) {
            #pragma unroll
            for (int r = 0; r < 4; ++r) { U[n * 4 + r] = u[r]; V[n * 4 + r] = v[r]; }
        }
    }
}

// ---------- per-edge output: sigmoid(U[src]+V[dst]+c) ----------
__global__ void k_edge_out(const int* __restrict__ ei, const float* __restrict__ U,
                           const float* __restrict__ V, const float* __restrict__ cvec,
                           float* __restrict__ out) {
    int idx = blockIdx.x * 256 + threadIdx.x;
    if (idx >= N_EDGES * 4) return;
    int e = idx >> 2, r = idx & 3;
    float val = U[ei[e] * 4 + r] + V[ei[N_EDGES + e] * 4 + r] + cvec[r];
    out[idx] = 1.f / (1.f + expf(-val));
}

extern "C" void kernel_launch(void* const* d_in, const int* in_sizes, int n_in,
                              void* d_out, int out_size, void* d_ws, size_t ws_size,
                              hipStream_t stream) {
    (void)in_sizes; (void)n_in; (void)out_size; (void)ws_size;
    const float* x      = (const float*)d_in[0];
    const int*   ei     = (const int*)d_in[1];
    const float* ef     = (const float*)d_in[2];
    const float* W1     = (const float*)d_in[3];
    const float* a_src1 = (const float*)d_in[4];
    const float* a_dst1 = (const float*)d_in[5];
    const float* We1    = (const float*)d_in[6];
    const float* a_e1   = (const float*)d_in[7];
    const float* b1     = (const float*)d_in[8];
    const float* W2     = (const float*)d_in[9];
    const float* a_src2 = (const float*)d_in[10];
    const float* a_dst2 = (const float*)d_in[11];
    const float* We2    = (const float*)d_in[12];
    const float* a_e2   = (const float*)d_in[13];
    const float* b2     = (const float*)d_in[14];
    const float* Wd1    = (const float*)d_in[15];
    const float* bd1    = (const float*)d_in[16];
    const float* Wd2    = (const float*)d_in[17];
    const float* bd2    = (const float*)d_in[18];
    float* out = (float*)d_out;

    // workspace layout
    float* A      = (float*)d_ws;                            // N*512 (xp current layer)
    float* z1     = A + (size_t)N_NODES * HC;                // N*512
    float* ae_all = z1 + (size_t)N_NODES * HC;               // E_TOT*4
    float* as_    = ae_all + (size_t)E_TOT * 4;              // N*4
    float* ad_    = as_ + N_NODES * 4;                       // N*4
    float* meanf  = ad_ + N_NODES * 4;                       // N*8
    float* cntf   = meanf + N_NODES * 8;                     // N
    float* q1     = cntf + N_NODES;                          // 32
    float* q2     = q1 + 32;                                 // 32
    float* Mm     = q2 + 32;                                 // 4096
    float* cv     = Mm + 4096;                               // 4
    float* U      = cv + 4;                                  // N*4
    float* V      = U + N_NODES * 4;                         // N*4
    int* row_start = (int*)(V + N_NODES * 4);                // N+1 (padded 20004)
    int* counts    = row_start + 20004;                      // N
    int* nxt       = counts + N_NODES;                       // N
    int* csr_src   = nxt + N_NODES;                          // E_TOT
    int* csr_eid   = csr_src + E_TOT;                        // E_TOT

    // ---- prep ----
    hipMemsetAsync(meanf, 0, (N_NODES * 8 + N_NODES) * sizeof(float), stream);
    hipMemsetAsync(counts, 0, N_NODES * sizeof(int), stream);
    k_mean_acc<<<(N_EDGES + 255) / 256, 256, 0, stream>>>(ei, ef, meanf, cntf);
    k_mean_div<<<(N_NODES * 8 + 255) / 256, 256, 0, stream>>>(meanf, cntf);
    k_prep_q<<<1, 64, 0, stream>>>(We1, a_e1, We2, a_e2, q1, q2);
    k_prep_M<<<16, 256, 0, stream>>>(Wd1, Wd2, bd1, bd2, Mm, cv);
    k_count<<<(E_TOT + 255) / 256, 256, 0, stream>>>(ei, counts);
    k_scan<<<1, 1024, 0, stream>>>(counts, row_start, nxt);
    k_scatter<<<(E_TOT + 255) / 256, 256, 0, stream>>>(ei, nxt, csr_src, csr_eid);

    // ---- layer 1 ----
    k_gemm<<<dim3(HC / 64, (N_NODES + 63) / 64), 256, 0, stream>>>(x, W1, A, N_NODES, FIN, HC);
    k_node_alpha<<<(N_NODES + 3) / 4, 256, 0, stream>>>(A, a_src1, a_dst1, as_, ad_);
    k_edge_ae<<<(E_TOT + 255) / 256, 256, 0, stream>>>(ei, ef, meanf, q1, ae_all);
    k_dst_fused<1><<<(N_NODES + 3) / 4, 256, 0, stream>>>(
        row_start, csr_src, csr_eid, A, ae_all, as_, ad_, b1, z1, nullptr, nullptr, nullptr);

    // ---- layer 2 (decoder UV fused into epilogue) ----
    k_gemm<<<dim3(HC / 64, (N_NODES + 63) / 64), 256, 0, stream>>>(z1, W2, A, N_NODES, HC, HC);
    k_node_alpha<<<(N_NODES + 3) / 4, 256, 0, stream>>>(A, a_src2, a_dst2, as_, ad_);
    k_edge_ae<<<(E_TOT + 255) / 256, 256, 0, stream>>>(ei, ef, meanf, q2, ae_all);
    k_dst_fused<2><<<(N_NODES + 3) / 4, 256, 0, stream>>>(
        row_start, csr_src, csr_eid, A, ae_all, as_, ad_, b2, nullptr, Mm, U, V);

    // ---- output ----
    k_edge_out<<<(N_EDGES * 4 + 255) / 256, 256, 0, stream>>>(ei, U, V, cv, out);
}

// Round 3
// 385.846 us; speedup vs baseline: 3.1090x; 1.5435x over previous
//
#include <hip/hip_runtime.h>
#include <hip/hip_bf16.h>
#include <math.h>

#define N_NODES 20000
#define N_EDGES 160000
#define FIN 64
#define EDGE_DIM 8
#define H_HEADS 4
#define C_CH 128
#define HC 512
#define NUM_RELS 4
#define E_TOT (N_EDGES + N_NODES)   // 180000

typedef __bf16 bf16x8 __attribute__((ext_vector_type(8)));
typedef float f32x4 __attribute__((ext_vector_type(4)));
typedef unsigned short u16x8 __attribute__((ext_vector_type(8)));

// ---------- fp32 -> bf16 ----------
__global__ void k_to_bf16(const float* __restrict__ in, __bf16* __restrict__ out, int n4) {
    int i = blockIdx.x * 256 + threadIdx.x;
    if (i >= n4) return;
    float4 v = *(const float4*)(in + (size_t)i * 4);
    bf16x8 dummy;
    __bf16 o[4] = {(__bf16)v.x, (__bf16)v.y, (__bf16)v.z, (__bf16)v.w};
    *(ushort2*)(out + (size_t)i * 4) = *(ushort2*)o;
    *(ushort2*)(out + (size_t)i * 4 + 2) = *(ushort2*)(o + 2);
    (void)dummy;
}

// ---------- W[K][N] fp32 -> Wt[N][K] bf16 ----------
__global__ void k_transpose_w(const float* __restrict__ W, __bf16* __restrict__ Wt,
                              int K, int N) {
    int tid = blockIdx.x * 256 + threadIdx.x;
    if (tid >= K * N) return;
    int n = tid / K, k = tid % K;
    Wt[(size_t)n * K + k] = (__bf16)W[(size_t)k * N + n];
}

// ---------- bf16 MFMA GEMM: C[M,HC] = A[M,K] @ Bt[HC,K]^T ----------
// tile 128x128, BK=32, 4 waves, 4x4 16x16 frags per wave. Grid: 1D nwg = 4*ceil(M/128).
#define LDP 40   // padded LDS row stride (bf16 elems): 80B -> conflict-free-ish
__global__ __launch_bounds__(256)
void k_gemm_bf16(const __bf16* __restrict__ A, const __bf16* __restrict__ Bt,
                 float* __restrict__ C, int M, int K) {
    __shared__ __bf16 As[128 * LDP];
    __shared__ __bf16 Bs[128 * LDP];

    // bijective XCD-chunk swizzle (8 XCDs)
    int nwg = gridDim.x;
    int f = blockIdx.x;
    int q = nwg >> 3, r = nwg & 7;
    int xcd = f & 7, idx = f >> 3;
    int wg = (xcd < r ? xcd * (q + 1) : r * (q + 1) + (xcd - r) * q) + idx;
    int by = wg >> 2, bx = wg & 3;          // 4 column blocks (HC=512 / 128)
    int br = by * 128, bc = bx * 128;

    const int t = threadIdx.x;
    const int lane = t & 63;
    const int wid = t >> 6;
    const int wr = wid >> 1, wc = wid & 1;  // 2x2 wave grid, 64x64 per wave
    const int l15 = lane & 15, lkg = lane >> 4;

    // staging coords: thread t covers row=t>>1, half=(t&1)*16 (16 bf16 = 2x16B)
    const int srow = t >> 1, shalf = (t & 1) * 16;
    const int agr = br + srow;
    const __bf16* Ap = A + (size_t)agr * K + shalf;
    const __bf16* Bp = Bt + (size_t)(bc + srow) * K + shalf;

    f32x4 acc[4][4] = {};

    for (int k0 = 0; k0 < K; k0 += 32) {
        // stage A (with M guard) and B
        u16x8 av0 = {}, av1 = {};
        if (agr < M) {
            av0 = *(const u16x8*)(Ap + k0);
            av1 = *(const u16x8*)(Ap + k0 + 8);
        }
        u16x8 bv0 = *(const u16x8*)(Bp + k0);
        u16x8 bv1 = *(const u16x8*)(Bp + k0 + 8);
        *(u16x8*)(As + srow * LDP + shalf) = av0;
        *(u16x8*)(As + srow * LDP + shalf + 8) = av1;
        *(u16x8*)(Bs + srow * LDP + shalf) = bv0;
        *(u16x8*)(Bs + srow * LDP + shalf + 8) = bv1;
        __syncthreads();

        bf16x8 a[4], b[4];
        #pragma unroll
        for (int m = 0; m < 4; ++m)
            a[m] = *(const bf16x8*)(As + (wr * 64 + m * 16 + l15) * LDP + lkg * 8);
        #pragma unroll
        for (int n = 0; n < 4; ++n)
            b[n] = *(const bf16x8*)(Bs + (wc * 64 + n * 16 + l15) * LDP + lkg * 8);
        #pragma unroll
        for (int m = 0; m < 4; ++m)
            #pragma unroll
            for (int n = 0; n < 4; ++n)
                acc[m][n] = __builtin_amdgcn_mfma_f32_16x16x32_bf16(a[m], b[n], acc[m][n], 0, 0, 0);
        __syncthreads();
    }

    // epilogue: C/D layout col=lane&15, row=(lane>>4)*4+reg
    #pragma unroll
    for (int m = 0; m < 4; ++m) {
        int rbase = br + wr * 64 + m * 16 + lkg * 4;
        #pragma unroll
        for (int n = 0; n < 4; ++n) {
            int col = bc + wc * 64 + n * 16 + l15;
            #pragma unroll
            for (int rg = 0; rg < 4; ++rg) {
                int gr = rbase + rg;
                if (gr < M) C[(size_t)gr * HC + col] = acc[m][n][rg];
            }
        }
    }
}

// ---------- self-loop mean edge features ----------
__global__ void k_mean_acc(const int* __restrict__ ei, const float* __restrict__ ef,
                           float* __restrict__ fsum, float* __restrict__ cnt) {
    int e = blockIdx.x * 256 + threadIdx.x;
    if (e >= N_EDGES) return;
    int dst = ei[N_EDGES + e];
    #pragma unroll
    for (int d = 0; d < 8; ++d) atomicAdd(fsum + dst * 8 + d, ef[(size_t)e * 8 + d]);
    atomicAdd(cnt + dst, 1.f);
}
__global__ void k_mean_div(float* __restrict__ fsum, const float* __restrict__ cnt) {
    int i = blockIdx.x * 256 + threadIdx.x;
    if (i >= N_NODES * 8) return;
    fsum[i] = fsum[i] / fmaxf(cnt[i >> 3], 1.f);
}

// ---------- q[h][d] = sum_c We[d, h*128+c] * a_e[h,c] ----------
__global__ void k_prep_q(const float* __restrict__ We1, const float* __restrict__ ae1,
                         const float* __restrict__ We2, const float* __restrict__ ae2,
                         float* __restrict__ q1, float* __restrict__ q2) {
    int t = threadIdx.x;
    if (t >= 64) return;
    const float* We = (t < 32) ? We1 : We2;
    const float* ae = (t < 32) ? ae1 : ae2;
    float* q = (t < 32) ? q1 : q2;
    int i = t & 31, h = i >> 3, d = i & 7;
    float s = 0.f;
    for (int c = 0; c < 128; ++c) s += We[d * 512 + h * 128 + c] * ae[h * 128 + c];
    q[i] = s;
}

// ---------- collapsed decoder: M = Wd1@Wd2 (1024x4), c = bd1@Wd2+bd2 ----------
__global__ void k_prep_M(const float* __restrict__ Wd1, const float* __restrict__ Wd2,
                         const float* __restrict__ bd1, const float* __restrict__ bd2,
                         float* __restrict__ M, float* __restrict__ cvec) {
    int tid = blockIdx.x * 256 + threadIdx.x;   // 4096 total
    int i = tid >> 2, r = tid & 3;
    float s = 0.f;
    for (int k = 0; k < 256; ++k) s += Wd1[i * 256 + k] * Wd2[k * 4 + r];
    M[tid] = s;
    if (tid < 4) {
        float c = 0.f;
        for (int k = 0; k < 256; ++k) c += bd1[k] * Wd2[k * 4 + tid];
        cvec[tid] = c + bd2[tid];
    }
}

// ---------- CSR build ----------
__global__ void k_count(const int* __restrict__ ei, int* __restrict__ counts) {
    int e = blockIdx.x * 256 + threadIdx.x;
    if (e >= E_TOT) return;
    int dst = (e < N_EDGES) ? ei[N_EDGES + e] : (e - N_EDGES);
    atomicAdd(counts + dst, 1);
}

__global__ __launch_bounds__(1024)
void k_scan(const int* __restrict__ counts, int* __restrict__ row_start,
            int* __restrict__ nxt) {
    __shared__ int part[1024];
    int t = threadIdx.x;
    int base = t * 20;
    int pre[20];
    int s = 0;
    #pragma unroll
    for (int i = 0; i < 20; ++i) {
        int idx = base + i;
        int c = (idx < N_NODES) ? counts[idx] : 0;
        pre[i] = s; s += c;
    }
    part[t] = s;
    __syncthreads();
    for (int off = 1; off < 1024; off <<= 1) {
        int v = (t >= off) ? part[t - off] : 0;
        __syncthreads();
        part[t] += v;
        __syncthreads();
    }
    int excl = (t == 0) ? 0 : part[t - 1];
    #pragma unroll
    for (int i = 0; i < 20; ++i) {
        int idx = base + i;
        if (idx < N_NODES) { int v = excl + pre[i]; row_start[idx] = v; nxt[idx] = v; }
    }
    if (t == 1023) row_start[N_NODES] = part[1023];
}

__global__ void k_scatter(const int* __restrict__ ei, int* __restrict__ nxt,
                          int* __restrict__ csr_src, int* __restrict__ csr_eid) {
    int e = blockIdx.x * 256 + threadIdx.x;
    if (e >= E_TOT) return;
    int src, dst;
    if (e < N_EDGES) { src = ei[e]; dst = ei[N_EDGES + e]; }
    else             { src = dst = e - N_EDGES; }
    int pos = atomicAdd(nxt + dst, 1);
    csr_src[pos] = src;
    csr_eid[pos] = e;
}

// ---------- per-node alpha_src / alpha_dst ----------
__global__ __launch_bounds__(256)
void k_node_alpha(const float* __restrict__ xp, const float* __restrict__ a_s,
                  const float* __restrict__ a_d, float* __restrict__ as_out,
                  float* __restrict__ ad_out) {
    int n = blockIdx.x * 4 + (threadIdx.x >> 6);
    int lane = threadIdx.x & 63;
    if (n >= N_NODES) return;
    int h = lane >> 4;
    const float* xpp = xp + (size_t)n * HC + lane * 8;
    float4 v0 = *(const float4*)xpp;
    float4 v1 = *(const float4*)(xpp + 4);
    const float* ap = a_s + h * C_CH + (lane & 15) * 8;
    const float* dp = a_d + h * C_CH + (lane & 15) * 8;
    float4 a0 = *(const float4*)ap, a1 = *(const float4*)(ap + 4);
    float4 d0 = *(const float4*)dp, d1 = *(const float4*)(dp + 4);
    float s = v0.x * a0.x + v0.y * a0.y + v0.z * a0.z + v0.w * a0.w +
              v1.x * a1.x + v1.y * a1.y + v1.z * a1.z + v1.w * a1.w;
    float d = v0.x * d0.x + v0.y * d0.y + v0.z * d0.z + v0.w * d0.w +
              v1.x * d1.x + v1.y * d1.y + v1.z * d1.z + v1.w * d1.w;
    #pragma unroll
    for (int off = 8; off; off >>= 1) {
        s += __shfl_xor(s, off);
        d += __shfl_xor(d, off);
    }
    if ((lane & 15) == 0) {
        as_out[n * 4 + h] = s;
        ad_out[n * 4 + h] = d;
    }
}

// ---------- alpha_e per edge ----------
__global__ void k_edge_ae(const int* __restrict__ ei, const float* __restrict__ ef,
                          const float* __restrict__ meanf, const float* __restrict__ q,
                          float* __restrict__ ae_all) {
    int e = blockIdx.x * 256 + threadIdx.x;
    if (e >= E_TOT) return;
    const float* fe = (e < N_EDGES) ? (ef + (size_t)e * 8)
                                    : (meanf + (size_t)(e - N_EDGES) * 8);
    float f[8];
    #pragma unroll
    for (int d = 0; d < 8; ++d) f[d] = fe[d];
    float4 o;
    float* op = &o.x;
    #pragma unroll
    for (int h = 0; h < 4; ++h) {
        float s = 0.f;
        #pragma unroll
        for (int d = 0; d < 8; ++d) s += f[d] * q[h * 8 + d];
        op[h] = s;
    }
    *(float4*)(ae_all + (size_t)e * 4) = o;
}

__device__ __forceinline__ void edge_alpha(int src, int eid, const float4 adn,
                                           const float* __restrict__ as_,
                                           const float* __restrict__ ae_all,
                                           float& a0, float& a1, float& a2, float& a3) {
    float4 asv = *(const float4*)(as_ + src * 4);
    float4 aev = *(const float4*)(ae_all + (size_t)eid * 4);
    a0 = asv.x + adn.x + aev.x; a0 = a0 > 0.f ? a0 : 0.2f * a0;
    a1 = asv.y + adn.y + aev.y; a1 = a1 > 0.f ? a1 : 0.2f * a1;
    a2 = asv.z + adn.z + aev.z; a2 = a2 > 0.f ? a2 : 0.2f * a2;
    a3 = asv.w + adn.w + aev.w; a3 = a3 > 0.f ? a3 : 0.2f * a3;
}

// ---------- fused per-dst: softmax + aggregate + ELU (+ decoder UV in layer 2) ----------
// LAYER==1 writes z as bf16 (only consumer is layer-2 GEMM).
template <int LAYER>
__global__ __launch_bounds__(256)
void k_dst_fused(const int* __restrict__ row_start, const int* __restrict__ csr_src,
                 const int* __restrict__ csr_eid, const float* __restrict__ xp,
                 const float* __restrict__ ae_all, const float* __restrict__ as_,
                 const float* __restrict__ ad_, const float* __restrict__ b,
                 __bf16* __restrict__ zb, const float* __restrict__ Mm,
                 float* __restrict__ U, float* __restrict__ V) {
    int n = blockIdx.x * 4 + (threadIdx.x >> 6);
    int lane = threadIdx.x & 63;
    if (n >= N_NODES) return;
    int rs = row_start[n], re = row_start[n + 1];
    float4 adn = *(const float4*)(ad_ + n * 4);
    int hl = lane >> 4;

    // pass A: per-head segment max
    float m0 = -1e30f, m1 = -1e30f, m2 = -1e30f, m3 = -1e30f;
    for (int base = rs; base < re; base += 64) {
        int i = base + lane;
        if (i < re) {
            float a0, a1, a2, a3;
            edge_alpha(csr_src[i], csr_eid[i], adn, as_, ae_all, a0, a1, a2, a3);
            m0 = fmaxf(m0, a0); m1 = fmaxf(m1, a1);
            m2 = fmaxf(m2, a2); m3 = fmaxf(m3, a3);
        }
    }
    #pragma unroll
    for (int off = 32; off; off >>= 1) {
        m0 = fmaxf(m0, __shfl_xor(m0, off));
        m1 = fmaxf(m1, __shfl_xor(m1, off));
        m2 = fmaxf(m2, __shfl_xor(m2, off));
        m3 = fmaxf(m3, __shfl_xor(m3, off));
    }

    // pass B: exp, denominator, weighted aggregation
    float d0 = 0.f, d1 = 0.f, d2 = 0.f, d3 = 0.f;
    float acc[8] = {};
    for (int base = rs; base < re; base += 64) {
        int i = base + lane;
        float e0 = 0.f, e1 = 0.f, e2 = 0.f, e3 = 0.f;
        int src = 0;
        if (i < re) {
            src = csr_src[i];
            float a0, a1, a2, a3;
            edge_alpha(src, csr_eid[i], adn, as_, ae_all, a0, a1, a2, a3);
            e0 = expf(a0 - m0); e1 = expf(a1 - m1);
            e2 = expf(a2 - m2); e3 = expf(a3 - m3);
            d0 += e0; d1 += e1; d2 += e2; d3 += e3;
        }
        int cn = min(64, re - base);
        for (int j = 0; j < cn; ++j) {
            float w0 = __shfl(e0, j), w1 = __shfl(e1, j);
            float w2 = __shfl(e2, j), w3 = __shfl(e3, j);
            int sj = __shfl(src, j);
            float w = (hl == 0) ? w0 : (hl == 1) ? w1 : (hl == 2) ? w2 : w3;
            const float* xs = xp + (size_t)sj * HC + lane * 8;
            float4 x0 = *(const float4*)xs, x1 = *(const float4*)(xs + 4);
            acc[0] += x0.x * w; acc[1] += x0.y * w; acc[2] += x0.z * w; acc[3] += x0.w * w;
            acc[4] += x1.x * w; acc[5] += x1.y * w; acc[6] += x1.z * w; acc[7] += x1.w * w;
        }
    }
    #pragma unroll
    for (int off = 32; off; off >>= 1) {
        d0 += __shfl_xor(d0, off); d1 += __shfl_xor(d1, off);
        d2 += __shfl_xor(d2, off); d3 += __shfl_xor(d3, off);
    }
    float den = (hl == 0) ? d0 : (hl == 1) ? d1 : (hl == 2) ? d2 : d3;
    float inv = 1.f / den;

    float z[8];
    const float* bp = b + lane * 8;
    #pragma unroll
    for (int k = 0; k < 8; ++k) {
        float v = acc[k] * inv + bp[k];
        z[k] = (v > 0.f) ? v : expm1f(v);
    }

    if (LAYER == 1) {
        bf16x8 zv;
        #pragma unroll
        for (int k = 0; k < 8; ++k) zv[k] = (__bf16)z[k];
        *(bf16x8*)(zb + (size_t)n * HC + lane * 8) = zv;
    } else {
        float u[4] = {}, v[4] = {};
        #pragma unroll
        for (int k = 0; k < 8; ++k) {
            int fidx = lane * 8 + k;
            #pragma unroll
            for (int r = 0; r < 4; ++r) {
                u[r] += z[k] * Mm[fidx * 4 + r];
                v[r] += z[k] * Mm[(512 + fidx) * 4 + r];
            }
        }
        #pragma unroll
        for (int r = 0; r < 4; ++r) {
            #pragma unroll
            for (int off = 32; off; off >>= 1) {
                u[r] += __shfl_xor(u[r], off);
                v[r] += __shfl_xor(v[r], off);
            }
        }
        if (lane == 0) {
            #pragma unroll
            for (int r = 0; r < 4; ++r) { U[n * 4 + r] = u[r]; V[n * 4 + r] = v[r]; }
        }
    }
}

// ---------- per-edge output ----------
__global__ void k_edge_out(const int* __restrict__ ei, const float* __restrict__ U,
                           const float* __restrict__ V, const float* __restrict__ cvec,
                           float* __restrict__ out) {
    int idx = blockIdx.x * 256 + threadIdx.x;
    if (idx >= N_EDGES * 4) return;
    int e = idx >> 2, r = idx & 3;
    float val = U[ei[e] * 4 + r] + V[ei[N_EDGES + e] * 4 + r] + cvec[r];
    out[idx] = 1.f / (1.f + expf(-val));
}

extern "C" void kernel_launch(void* const* d_in, const int* in_sizes, int n_in,
                              void* d_out, int out_size, void* d_ws, size_t ws_size,
                              hipStream_t stream) {
    (void)in_sizes; (void)n_in; (void)out_size; (void)ws_size;
    const float* x      = (const float*)d_in[0];
    const int*   ei     = (const int*)d_in[1];
    const float* ef     = (const float*)d_in[2];
    const float* W1     = (const float*)d_in[3];
    const float* a_src1 = (const float*)d_in[4];
    const float* a_dst1 = (const float*)d_in[5];
    const float* We1    = (const float*)d_in[6];
    const float* a_e1   = (const float*)d_in[7];
    const float* b1     = (const float*)d_in[8];
    const float* W2     = (const float*)d_in[9];
    const float* a_src2 = (const float*)d_in[10];
    const float* a_dst2 = (const float*)d_in[11];
    const float* We2    = (const float*)d_in[12];
    const float* a_e2   = (const float*)d_in[13];
    const float* b2     = (const float*)d_in[14];
    const float* Wd1    = (const float*)d_in[15];
    const float* bd1    = (const float*)d_in[16];
    const float* Wd2    = (const float*)d_in[17];
    const float* bd2    = (const float*)d_in[18];
    float* out = (float*)d_out;

    // workspace layout (all segments 16B-aligned)
    float* A      = (float*)d_ws;                            // N*512 fp32 (xp current layer)
    float* ae_all = A + (size_t)N_NODES * HC;                // E_TOT*4
    float* as_    = ae_all + (size_t)E_TOT * 4;              // N*4
    float* ad_    = as_ + N_NODES * 4;                       // N*4
    float* meanf  = ad_ + N_NODES * 4;                       // N*8
    float* cntf   = meanf + N_NODES * 8;                     // N
    float* q1     = cntf + N_NODES;                          // 32
    float* q2     = q1 + 32;                                 // 32
    float* Mm     = q2 + 32;                                 // 4096
    float* cv     = Mm + 4096;                               // 4
    float* U      = cv + 4;                                  // N*4
    float* V      = U + N_NODES * 4;                         // N*4
    int* row_start = (int*)(V + N_NODES * 4);                // 20004
    int* counts    = row_start + 20004;                      // N
    int* nxt       = counts + N_NODES;                       // N
    int* csr_src   = nxt + N_NODES;                          // E_TOT
    int* csr_eid   = csr_src + E_TOT;                        // E_TOT
    __bf16* xb   = (__bf16*)(csr_eid + E_TOT);               // N*64
    __bf16* z1b  = xb + (size_t)N_NODES * FIN;               // N*512
    __bf16* Wt1  = z1b + (size_t)N_NODES * HC;               // 512*64
    __bf16* Wt2  = Wt1 + HC * FIN;                           // 512*512

    // ---- prep ----
    hipMemsetAsync(meanf, 0, (N_NODES * 8 + N_NODES) * sizeof(float), stream);
    hipMemsetAsync(counts, 0, N_NODES * sizeof(int), stream);
    k_mean_acc<<<(N_EDGES + 255) / 256, 256, 0, stream>>>(ei, ef, meanf, cntf);
    k_mean_div<<<(N_NODES * 8 + 255) / 256, 256, 0, stream>>>(meanf, cntf);
    k_prep_q<<<1, 64, 0, stream>>>(We1, a_e1, We2, a_e2, q1, q2);
    k_prep_M<<<16, 256, 0, stream>>>(Wd1, Wd2, bd1, bd2, Mm, cv);
    k_count<<<(E_TOT + 255) / 256, 256, 0, stream>>>(ei, counts);
    k_scan<<<1, 1024, 0, stream>>>(counts, row_start, nxt);
    k_scatter<<<(E_TOT + 255) / 256, 256, 0, stream>>>(ei, nxt, csr_src, csr_eid);
    k_to_bf16<<<(N_NODES * FIN / 4 + 255) / 256, 256, 0, stream>>>(x, xb, N_NODES * FIN / 4);
    k_transpose_w<<<(HC * FIN + 255) / 256, 256, 0, stream>>>(W1, Wt1, FIN, HC);
    k_transpose_w<<<(HC * HC + 255) / 256, 256, 0, stream>>>(W2, Wt2, HC, HC);

    const int nby = (N_NODES + 127) / 128;   // 157
    const int nwg = nby * 4;                 // 628

    // ---- layer 1 ----
    k_gemm_bf16<<<nwg, 256, 0, stream>>>(xb, Wt1, A, N_NODES, FIN);
    k_node_alpha<<<(N_NODES + 3) / 4, 256, 0, stream>>>(A, a_src1, a_dst1, as_, ad_);
    k_edge_ae<<<(E_TOT + 255) / 256, 256, 0, stream>>>(ei, ef, meanf, q1, ae_all);
    k_dst_fused<1><<<(N_NODES + 3) / 4, 256, 0, stream>>>(
        row_start, csr_src, csr_eid, A, ae_all, as_, ad_, b1, z1b, nullptr, nullptr, nullptr);

    // ---- layer 2 ----
    k_gemm_bf16<<<nwg, 256, 0, stream>>>(z1b, Wt2, A, N_NODES, HC);
    k_node_alpha<<<(N_NODES + 3) / 4, 256, 0, stream>>>(A, a_src2, a_dst2, as_, ad_);
    k_edge_ae<<<(E_TOT + 255) / 256, 256, 0, stream>>>(ei, ef, meanf, q2, ae_all);
    k_dst_fused<2><<<(N_NODES + 3) / 4, 256, 0, stream>>>(
        row_start, csr_src, csr_eid, A, ae_all, as_, ad_, b2, nullptr, Mm, U, V);

    // ---- output ----
    k_edge_out<<<(N_EDGES * 4 + 255) / 256, 256, 0, stream>>>(ei, U, V, cv, out);
}

// Round 4
// 344.499 us; speedup vs baseline: 3.4822x; 1.1200x over previous
//
#include <hip/hip_runtime.h>
#include <hip/hip_bf16.h>
#include <math.h>

#define N_NODES 20000
#define N_EDGES 160000
#define FIN 64
#define EDGE_DIM 8
#define H_HEADS 4
#define C_CH 128
#define HC 512
#define NUM_RELS 4
#define E_TOT (N_EDGES + N_NODES)   // 180000

typedef __bf16 bf16x8 __attribute__((ext_vector_type(8)));
typedef float f32x4 __attribute__((ext_vector_type(4)));
typedef unsigned short u16x8 __attribute__((ext_vector_type(8)));

// ---------- fp32 -> bf16 ----------
__global__ void k_to_bf16(const float* __restrict__ in, __bf16* __restrict__ out, int n4) {
    int i = blockIdx.x * 256 + threadIdx.x;
    if (i >= n4) return;
    float4 v = *(const float4*)(in + (size_t)i * 4);
    __bf16 o[4] = {(__bf16)v.x, (__bf16)v.y, (__bf16)v.z, (__bf16)v.w};
    *(ushort2*)(out + (size_t)i * 4) = *(ushort2*)o;
    *(ushort2*)(out + (size_t)i * 4 + 2) = *(ushort2*)(o + 2);
}

// ---------- W[K][N] fp32 -> Wt[N][K] bf16 ----------
__global__ void k_transpose_w(const float* __restrict__ W, __bf16* __restrict__ Wt,
                              int K, int N) {
    int tid = blockIdx.x * 256 + threadIdx.x;
    if (tid >= K * N) return;
    int n = tid / K, k = tid % K;
    Wt[(size_t)n * K + k] = (__bf16)W[(size_t)k * N + n];
}

// ---------- bf16 MFMA GEMM: Cb[M,HC] = A[M,K] @ Bt[HC,K]^T  (bf16 output) ----------
#define LDP 40
__global__ __launch_bounds__(256)
void k_gemm_bf16(const __bf16* __restrict__ A, const __bf16* __restrict__ Bt,
                 __bf16* __restrict__ Cb, int M, int K) {
    __shared__ __bf16 As[128 * LDP];
    __shared__ __bf16 Bs[128 * LDP];

    int nwg = gridDim.x;
    int f = blockIdx.x;
    int q = nwg >> 3, r = nwg & 7;
    int xcd = f & 7, idx = f >> 3;
    int wg = (xcd < r ? xcd * (q + 1) : r * (q + 1) + (xcd - r) * q) + idx;
    int by = wg >> 2, bx = wg & 3;
    int br = by * 128, bc = bx * 128;

    const int t = threadIdx.x;
    const int lane = t & 63;
    const int wid = t >> 6;
    const int wr = wid >> 1, wc = wid & 1;
    const int l15 = lane & 15, lkg = lane >> 4;

    const int srow = t >> 1, shalf = (t & 1) * 16;
    const int agr = br + srow;
    const __bf16* Ap = A + (size_t)agr * K + shalf;
    const __bf16* Bp = Bt + (size_t)(bc + srow) * K + shalf;

    f32x4 acc[4][4] = {};

    for (int k0 = 0; k0 < K; k0 += 32) {
        u16x8 av0 = {}, av1 = {};
        if (agr < M) {
            av0 = *(const u16x8*)(Ap + k0);
            av1 = *(const u16x8*)(Ap + k0 + 8);
        }
        u16x8 bv0 = *(const u16x8*)(Bp + k0);
        u16x8 bv1 = *(const u16x8*)(Bp + k0 + 8);
        *(u16x8*)(As + srow * LDP + shalf) = av0;
        *(u16x8*)(As + srow * LDP + shalf + 8) = av1;
        *(u16x8*)(Bs + srow * LDP + shalf) = bv0;
        *(u16x8*)(Bs + srow * LDP + shalf + 8) = bv1;
        __syncthreads();

        bf16x8 a[4], b[4];
        #pragma unroll
        for (int m = 0; m < 4; ++m)
            a[m] = *(const bf16x8*)(As + (wr * 64 + m * 16 + l15) * LDP + lkg * 8);
        #pragma unroll
        for (int n = 0; n < 4; ++n)
            b[n] = *(const bf16x8*)(Bs + (wc * 64 + n * 16 + l15) * LDP + lkg * 8);
        #pragma unroll
        for (int m = 0; m < 4; ++m)
            #pragma unroll
            for (int n = 0; n < 4; ++n)
                acc[m][n] = __builtin_amdgcn_mfma_f32_16x16x32_bf16(a[m], b[n], acc[m][n], 0, 0, 0);
        __syncthreads();
    }

    #pragma unroll
    for (int m = 0; m < 4; ++m) {
        int rbase = br + wr * 64 + m * 16 + lkg * 4;
        #pragma unroll
        for (int n = 0; n < 4; ++n) {
            int col = bc + wc * 64 + n * 16 + l15;
            #pragma unroll
            for (int rg = 0; rg < 4; ++rg) {
                int gr = rbase + rg;
                if (gr < M) Cb[(size_t)gr * HC + col] = (__bf16)acc[m][n][rg];
            }
        }
    }
}

// ---------- self-loop mean edge features ----------
__global__ void k_mean_acc(const int* __restrict__ ei, const float* __restrict__ ef,
                           float* __restrict__ fsum, float* __restrict__ cnt) {
    int e = blockIdx.x * 256 + threadIdx.x;
    if (e >= N_EDGES) return;
    int dst = ei[N_EDGES + e];
    #pragma unroll
    for (int d = 0; d < 8; ++d) atomicAdd(fsum + dst * 8 + d, ef[(size_t)e * 8 + d]);
    atomicAdd(cnt + dst, 1.f);
}
__global__ void k_mean_div(float* __restrict__ fsum, const float* __restrict__ cnt) {
    int i = blockIdx.x * 256 + threadIdx.x;
    if (i >= N_NODES * 8) return;
    fsum[i] = fsum[i] / fmaxf(cnt[i >> 3], 1.f);
}

// ---------- q[h][d] = sum_c We[d, h*128+c] * a_e[h,c] ----------
__global__ void k_prep_q(const float* __restrict__ We1, const float* __restrict__ ae1,
                         const float* __restrict__ We2, const float* __restrict__ ae2,
                         float* __restrict__ q1, float* __restrict__ q2) {
    int t = threadIdx.x;
    if (t >= 64) return;
    const float* We = (t < 32) ? We1 : We2;
    const float* ae = (t < 32) ? ae1 : ae2;
    float* q = (t < 32) ? q1 : q2;
    int i = t & 31, h = i >> 3, d = i & 7;
    float s = 0.f;
    for (int c = 0; c < 128; ++c) s += We[d * 512 + h * 128 + c] * ae[h * 128 + c];
    q[i] = s;
}

// ---------- collapsed decoder: M = Wd1@Wd2 (1024x4), c = bd1@Wd2+bd2 ----------
__global__ void k_prep_M(const float* __restrict__ Wd1, const float* __restrict__ Wd2,
                         const float* __restrict__ bd1, const float* __restrict__ bd2,
                         float* __restrict__ M, float* __restrict__ cvec) {
    int tid = blockIdx.x * 256 + threadIdx.x;   // 4096 total
    int i = tid >> 2, r = tid & 3;
    float s = 0.f;
    for (int k = 0; k < 256; ++k) s += Wd1[i * 256 + k] * Wd2[k * 4 + r];
    M[tid] = s;
    if (tid < 4) {
        float c = 0.f;
        for (int k = 0; k < 256; ++k) c += bd1[k] * Wd2[k * 4 + tid];
        cvec[tid] = c + bd2[tid];
    }
}

// ---------- CSR build ----------
__global__ void k_count(const int* __restrict__ ei, int* __restrict__ counts) {
    int e = blockIdx.x * 256 + threadIdx.x;
    if (e >= E_TOT) return;
    int dst = (e < N_EDGES) ? ei[N_EDGES + e] : (e - N_EDGES);
    atomicAdd(counts + dst, 1);
}

__global__ __launch_bounds__(1024)
void k_scan(const int* __restrict__ counts, int* __restrict__ row_start,
            int* __restrict__ nxt) {
    __shared__ int part[1024];
    int t = threadIdx.x;
    int base = t * 20;
    int pre[20];
    int s = 0;
    #pragma unroll
    for (int i = 0; i < 20; ++i) {
        int idx = base + i;
        int c = (idx < N_NODES) ? counts[idx] : 0;
        pre[i] = s; s += c;
    }
    part[t] = s;
    __syncthreads();
    for (int off = 1; off < 1024; off <<= 1) {
        int v = (t >= off) ? part[t - off] : 0;
        __syncthreads();
        part[t] += v;
        __syncthreads();
    }
    int excl = (t == 0) ? 0 : part[t - 1];
    #pragma unroll
    for (int i = 0; i < 20; ++i) {
        int idx = base + i;
        if (idx < N_NODES) { int v = excl + pre[i]; row_start[idx] = v; nxt[idx] = v; }
    }
    if (t == 1023) row_start[N_NODES] = part[1023];
}

__global__ void k_scatter(const int* __restrict__ ei, int* __restrict__ nxt,
                          int* __restrict__ csr_src, int* __restrict__ csr_eid) {
    int e = blockIdx.x * 256 + threadIdx.x;
    if (e >= E_TOT) return;
    int src, dst;
    if (e < N_EDGES) { src = ei[e]; dst = ei[N_EDGES + e]; }
    else             { src = dst = e - N_EDGES; }
    int pos = atomicAdd(nxt + dst, 1);
    csr_src[pos] = src;
    csr_eid[pos] = e;
}

// ---------- per-node alpha_src / alpha_dst (bf16 xp) ----------
__global__ __launch_bounds__(256)
void k_node_alpha(const __bf16* __restrict__ xp, const float* __restrict__ a_s,
                  const float* __restrict__ a_d, float* __restrict__ as_out,
                  float* __restrict__ ad_out) {
    int n = blockIdx.x * 4 + (threadIdx.x >> 6);
    int lane = threadIdx.x & 63;
    if (n >= N_NODES) return;
    int h = lane >> 4;
    bf16x8 xv = *(const bf16x8*)(xp + (size_t)n * HC + lane * 8);
    const float* ap = a_s + h * C_CH + (lane & 15) * 8;
    const float* dp = a_d + h * C_CH + (lane & 15) * 8;
    float4 a0 = *(const float4*)ap, a1 = *(const float4*)(ap + 4);
    float4 d0 = *(const float4*)dp, d1 = *(const float4*)(dp + 4);
    float v[8];
    #pragma unroll
    for (int k = 0; k < 8; ++k) v[k] = (float)xv[k];
    float s = v[0] * a0.x + v[1] * a0.y + v[2] * a0.z + v[3] * a0.w +
              v[4] * a1.x + v[5] * a1.y + v[6] * a1.z + v[7] * a1.w;
    float d = v[0] * d0.x + v[1] * d0.y + v[2] * d0.z + v[3] * d0.w +
              v[4] * d1.x + v[5] * d1.y + v[6] * d1.z + v[7] * d1.w;
    #pragma unroll
    for (int off = 8; off; off >>= 1) {
        s += __shfl_xor(s, off);
        d += __shfl_xor(d, off);
    }
    if ((lane & 15) == 0) {
        as_out[n * 4 + h] = s;
        ad_out[n * 4 + h] = d;
    }
}

// ---------- alpha_e per edge ----------
__global__ void k_edge_ae(const int* __restrict__ ei, const float* __restrict__ ef,
                          const float* __restrict__ meanf, const float* __restrict__ q,
                          float* __restrict__ ae_all) {
    int e = blockIdx.x * 256 + threadIdx.x;
    if (e >= E_TOT) return;
    const float* fe = (e < N_EDGES) ? (ef + (size_t)e * 8)
                                    : (meanf + (size_t)(e - N_EDGES) * 8);
    float f[8];
    #pragma unroll
    for (int d = 0; d < 8; ++d) f[d] = fe[d];
    float4 o;
    float* op = &o.x;
    #pragma unroll
    for (int h = 0; h < 4; ++h) {
        float s = 0.f;
        #pragma unroll
        for (int d = 0; d < 8; ++d) s += f[d] * q[h * 8 + d];
        op[h] = s;
    }
    *(float4*)(ae_all + (size_t)e * 4) = o;
}

__device__ __forceinline__ void edge_alpha(int src, int eid, const float4 adn,
                                           const float* __restrict__ as_,
                                           const float* __restrict__ ae_all,
                                           float& a0, float& a1, float& a2, float& a3) {
    float4 asv = *(const float4*)(as_ + src * 4);
    float4 aev = *(const float4*)(ae_all + (size_t)eid * 4);
    a0 = asv.x + adn.x + aev.x; a0 = a0 > 0.f ? a0 : 0.2f * a0;
    a1 = asv.y + adn.y + aev.y; a1 = a1 > 0.f ? a1 : 0.2f * a1;
    a2 = asv.z + adn.z + aev.z; a2 = a2 > 0.f ? a2 : 0.2f * a2;
    a3 = asv.w + adn.w + aev.w; a3 = a3 > 0.f ? a3 : 0.2f * a3;
}

// ---------- fused per-dst: softmax + aggregate (bf16 gather) + ELU (+ UV in L2) ----------
template <int LAYER>
__global__ __launch_bounds__(256)
void k_dst_fused(const int* __restrict__ row_start, const int* __restrict__ csr_src,
                 const int* __restrict__ csr_eid, const __bf16* __restrict__ xp,
                 const float* __restrict__ ae_all, const float* __restrict__ as_,
                 const float* __restrict__ ad_, const float* __restrict__ b,
                 __bf16* __restrict__ zb, const float* __restrict__ Mm,
                 float* __restrict__ U, float* __restrict__ V) {
    int n = blockIdx.x * 4 + (threadIdx.x >> 6);
    int lane = threadIdx.x & 63;
    if (n >= N_NODES) return;
    int rs = row_start[n], re = row_start[n + 1];
    float4 adn = *(const float4*)(ad_ + n * 4);
    int hl = lane >> 4;

    // pass A: per-head segment max
    float m0 = -1e30f, m1 = -1e30f, m2 = -1e30f, m3 = -1e30f;
    for (int base = rs; base < re; base += 64) {
        int i = base + lane;
        if (i < re) {
            float a0, a1, a2, a3;
            edge_alpha(csr_src[i], csr_eid[i], adn, as_, ae_all, a0, a1, a2, a3);
            m0 = fmaxf(m0, a0); m1 = fmaxf(m1, a1);
            m2 = fmaxf(m2, a2); m3 = fmaxf(m3, a3);
        }
    }
    #pragma unroll
    for (int off = 32; off; off >>= 1) {
        m0 = fmaxf(m0, __shfl_xor(m0, off));
        m1 = fmaxf(m1, __shfl_xor(m1, off));
        m2 = fmaxf(m2, __shfl_xor(m2, off));
        m3 = fmaxf(m3, __shfl_xor(m3, off));
    }

    // pass B: exp, denominator, weighted aggregation (bf16 rows, fp32 accum)
    float d0 = 0.f, d1 = 0.f, d2 = 0.f, d3 = 0.f;
    float acc[8] = {};
    for (int base = rs; base < re; base += 64) {
        int i = base + lane;
        float e0 = 0.f, e1 = 0.f, e2 = 0.f, e3 = 0.f;
        int src = 0;
        if (i < re) {
            src = csr_src[i];
            float a0, a1, a2, a3;
            edge_alpha(src, csr_eid[i], adn, as_, ae_all, a0, a1, a2, a3);
            e0 = expf(a0 - m0); e1 = expf(a1 - m1);
            e2 = expf(a2 - m2); e3 = expf(a3 - m3);
            d0 += e0; d1 += e1; d2 += e2; d3 += e3;
        }
        int cn = min(64, re - base);
        for (int j = 0; j < cn; ++j) {
            float w0 = __shfl(e0, j), w1 = __shfl(e1, j);
            float w2 = __shfl(e2, j), w3 = __shfl(e3, j);
            int sj = __shfl(src, j);
            float w = (hl == 0) ? w0 : (hl == 1) ? w1 : (hl == 2) ? w2 : w3;
            bf16x8 xv = *(const bf16x8*)(xp + (size_t)sj * HC + lane * 8);
            #pragma unroll
            for (int k = 0; k < 8; ++k) acc[k] += (float)xv[k] * w;
        }
    }
    #pragma unroll
    for (int off = 32; off; off >>= 1) {
        d0 += __shfl_xor(d0, off); d1 += __shfl_xor(d1, off);
        d2 += __shfl_xor(d2, off); d3 += __shfl_xor(d3, off);
    }
    float den = (hl == 0) ? d0 : (hl == 1) ? d1 : (hl == 2) ? d2 : d3;
    float inv = 1.f / den;

    float z[8];
    const float* bp = b + lane * 8;
    #pragma unroll
    for (int k = 0; k < 8; ++k) {
        float v = acc[k] * inv + bp[k];
        z[k] = (v > 0.f) ? v : expm1f(v);
    }

    if (LAYER == 1) {
        bf16x8 zv;
        #pragma unroll
        for (int k = 0; k < 8; ++k) zv[k] = (__bf16)z[k];
        *(bf16x8*)(zb + (size_t)n * HC + lane * 8) = zv;
    } else {
        float u[4] = {}, v[4] = {};
        #pragma unroll
        for (int k = 0; k < 8; ++k) {
            int fidx = lane * 8 + k;
            #pragma unroll
            for (int r = 0; r < 4; ++r) {
                u[r] += z[k] * Mm[fidx * 4 + r];
                v[r] += z[k] * Mm[(512 + fidx) * 4 + r];
            }
        }
        #pragma unroll
        for (int r = 0; r < 4; ++r) {
            #pragma unroll
            for (int off = 32; off; off >>= 1) {
                u[r] += __shfl_xor(u[r], off);
                v[r] += __shfl_xor(v[r], off);
            }
        }
        if (lane == 0) {
            #pragma unroll
            for (int r = 0; r < 4; ++r) { U[n * 4 + r] = u[r]; V[n * 4 + r] = v[r]; }
        }
    }
}

// ---------- per-edge output ----------
__global__ void k_edge_out(const int* __restrict__ ei, const float* __restrict__ U,
                           const float* __restrict__ V, const float* __restrict__ cvec,
                           float* __restrict__ out) {
    int idx = blockIdx.x * 256 + threadIdx.x;
    if (idx >= N_EDGES * 4) return;
    int e = idx >> 2, r = idx & 3;
    float val = U[ei[e] * 4 + r] + V[ei[N_EDGES + e] * 4 + r] + cvec[r];
    out[idx] = 1.f / (1.f + expf(-val));
}

extern "C" void kernel_launch(void* const* d_in, const int* in_sizes, int n_in,
                              void* d_out, int out_size, void* d_ws, size_t ws_size,
                              hipStream_t stream) {
    (void)in_sizes; (void)n_in; (void)out_size; (void)ws_size;
    const float* x      = (const float*)d_in[0];
    const int*   ei     = (const int*)d_in[1];
    const float* ef     = (const float*)d_in[2];
    const float* W1     = (const float*)d_in[3];
    const float* a_src1 = (const float*)d_in[4];
    const float* a_dst1 = (const float*)d_in[5];
    const float* We1    = (const float*)d_in[6];
    const float* a_e1   = (const float*)d_in[7];
    const float* b1     = (const float*)d_in[8];
    const float* W2     = (const float*)d_in[9];
    const float* a_src2 = (const float*)d_in[10];
    const float* a_dst2 = (const float*)d_in[11];
    const float* We2    = (const float*)d_in[12];
    const float* a_e2   = (const float*)d_in[13];
    const float* b2     = (const float*)d_in[14];
    const float* Wd1    = (const float*)d_in[15];
    const float* bd1    = (const float*)d_in[16];
    const float* Wd2    = (const float*)d_in[17];
    const float* bd2    = (const float*)d_in[18];
    float* out = (float*)d_out;

    // workspace layout
    float* ae_all = (float*)d_ws;                            // E_TOT*4
    float* as_    = ae_all + (size_t)E_TOT * 4;              // N*4
    float* ad_    = as_ + N_NODES * 4;                       // N*4
    float* meanf  = ad_ + N_NODES * 4;                       // N*8
    float* cntf   = meanf + N_NODES * 8;                     // N
    float* q1     = cntf + N_NODES;                          // 32
    float* q2     = q1 + 32;                                 // 32
    float* Mm     = q2 + 32;                                 // 4096
    float* cv     = Mm + 4096;                               // 4
    float* U      = cv + 4;                                  // N*4
    float* V      = U + N_NODES * 4;                         // N*4
    int* row_start = (int*)(V + N_NODES * 4);                // 20004
    int* counts    = row_start + 20004;                      // N
    int* nxt       = counts + N_NODES;                       // N
    int* csr_src   = nxt + N_NODES;                          // E_TOT
    int* csr_eid   = csr_src + E_TOT;                        // E_TOT
    __bf16* xb   = (__bf16*)(csr_eid + E_TOT);               // N*64
    __bf16* Ab   = xb + (size_t)N_NODES * FIN;               // N*512 (xp current layer, bf16)
    __bf16* z1b  = Ab + (size_t)N_NODES * HC;                // N*512
    __bf16* Wt1  = z1b + (size_t)N_NODES * HC;               // 512*64
    __bf16* Wt2  = Wt1 + HC * FIN;                           // 512*512

    // ---- prep ----
    hipMemsetAsync(meanf, 0, (N_NODES * 8 + N_NODES) * sizeof(float), stream);
    hipMemsetAsync(counts, 0, N_NODES * sizeof(int), stream);
    k_mean_acc<<<(N_EDGES + 255) / 256, 256, 0, stream>>>(ei, ef, meanf, cntf);
    k_mean_div<<<(N_NODES * 8 + 255) / 256, 256, 0, stream>>>(meanf, cntf);
    k_prep_q<<<1, 64, 0, stream>>>(We1, a_e1, We2, a_e2, q1, q2);
    k_prep_M<<<16, 256, 0, stream>>>(Wd1, Wd2, bd1, bd2, Mm, cv);
    k_count<<<(E_TOT + 255) / 256, 256, 0, stream>>>(ei, counts);
    k_scan<<<1, 1024, 0, stream>>>(counts, row_start, nxt);
    k_scatter<<<(E_TOT + 255) / 256, 256, 0, stream>>>(ei, nxt, csr_src, csr_eid);
    k_to_bf16<<<(N_NODES * FIN / 4 + 255) / 256, 256, 0, stream>>>(x, xb, N_NODES * FIN / 4);
    k_transpose_w<<<(HC * FIN + 255) / 256, 256, 0, stream>>>(W1, Wt1, FIN, HC);
    k_transpose_w<<<(HC * HC + 255) / 256, 256, 0, stream>>>(W2, Wt2, HC, HC);

    const int nby = (N_NODES + 127) / 128;   // 157
    const int nwg = nby * 4;                 // 628

    // ---- layer 1 ----
    k_gemm_bf16<<<nwg, 256, 0, stream>>>(xb, Wt1, Ab, N_NODES, FIN);
    k_node_alpha<<<(N_NODES + 3) / 4, 256, 0, stream>>>(Ab, a_src1, a_dst1, as_, ad_);
    k_edge_ae<<<(E_TOT + 255) / 256, 256, 0, stream>>>(ei, ef, meanf, q1, ae_all);
    k_dst_fused<1><<<(N_NODES + 3) / 4, 256, 0, stream>>>(
        row_start, csr_src, csr_eid, Ab, ae_all, as_, ad_, b1, z1b, nullptr, nullptr, nullptr);

    // ---- layer 2 ----
    k_gemm_bf16<<<nwg, 256, 0, stream>>>(z1b, Wt2, Ab, N_NODES, HC);
    k_node_alpha<<<(N_NODES + 3) / 4, 256, 0, stream>>>(Ab, a_src2, a_dst2, as_, ad_);
    k_edge_ae<<<(E_TOT + 255) / 256, 256, 0, stream>>>(ei, ef, meanf, q2, ae_all);
    k_dst_fused<2><<<(N_NODES + 3) / 4, 256, 0, stream>>>(
        row_start, csr_src, csr_eid, Ab, ae_all, as_, ad_, b2, nullptr, Mm, U, V);

    // ---- output ----
    k_edge_out<<<(N_EDGES * 4 + 255) / 256, 256, 0, stream>>>(ei, U, V, cv, out);
}

// Round 5
// 274.110 us; speedup vs baseline: 4.3764x; 1.2568x over previous
//
#include <hip/hip_runtime.h>
#include <hip/hip_bf16.h>
#include <math.h>

#define N_NODES 20000
#define N_EDGES 160000
#define FIN 64
#define EDGE_DIM 8
#define H_HEADS 4
#define C_CH 128
#define HC 512
#define NUM_RELS 4
#define E_TOT (N_EDGES + N_NODES)   // 180000

typedef __bf16 bf16x8 __attribute__((ext_vector_type(8)));
typedef float f32x4 __attribute__((ext_vector_type(4)));
typedef unsigned short u16x8 __attribute__((ext_vector_type(8)));

// ---------- combined dtype conversions: x->bf16, W1->Wt1, W2->Wt2 ----------
#define NX4 (N_NODES * FIN / 4)          // 320000
#define W1T (HC * FIN)                   // 32768
#define W2T (HC * HC)                    // 262144
__global__ void k_cvt(const float* __restrict__ x, __bf16* __restrict__ xb,
                      const float* __restrict__ W1, __bf16* __restrict__ Wt1,
                      const float* __restrict__ W2, __bf16* __restrict__ Wt2) {
    int tid = blockIdx.x * 256 + threadIdx.x;
    if (tid < NX4) {
        float4 v = *(const float4*)(x + (size_t)tid * 4);
        __bf16 o[4] = {(__bf16)v.x, (__bf16)v.y, (__bf16)v.z, (__bf16)v.w};
        *(ushort2*)(xb + (size_t)tid * 4) = *(ushort2*)o;
        *(ushort2*)(xb + (size_t)tid * 4 + 2) = *(ushort2*)(o + 2);
    } else if (tid < NX4 + W1T) {
        int t = tid - NX4;
        int n = t / FIN, k = t % FIN;
        Wt1[n * FIN + k] = (__bf16)W1[(size_t)k * HC + n];
    } else if (tid < NX4 + W1T + W2T) {
        int t = tid - NX4 - W1T;
        int n = t >> 9, k = t & 511;
        Wt2[n * HC + k] = (__bf16)W2[(size_t)k * HC + n];
    }
}

// ---------- bf16 MFMA GEMM: Cb[M,HC] = A[M,K] @ Bt[HC,K]^T  (bf16 output) ----------
#define LDP 40
__global__ __launch_bounds__(256)
void k_gemm_bf16(const __bf16* __restrict__ A, const __bf16* __restrict__ Bt,
                 __bf16* __restrict__ Cb, int M, int K) {
    __shared__ __bf16 As[128 * LDP];
    __shared__ __bf16 Bs[128 * LDP];

    int nwg = gridDim.x;
    int f = blockIdx.x;
    int q = nwg >> 3, r = nwg & 7;
    int xcd = f & 7, idx = f >> 3;
    int wg = (xcd < r ? xcd * (q + 1) : r * (q + 1) + (xcd - r) * q) + idx;
    int by = wg >> 2, bx = wg & 3;
    int br = by * 128, bc = bx * 128;

    const int t = threadIdx.x;
    const int lane = t & 63;
    const int wid = t >> 6;
    const int wr = wid >> 1, wc = wid & 1;
    const int l15 = lane & 15, lkg = lane >> 4;

    const int srow = t >> 1, shalf = (t & 1) * 16;
    const int agr = br + srow;
    const __bf16* Ap = A + (size_t)agr * K + shalf;
    const __bf16* Bp = Bt + (size_t)(bc + srow) * K + shalf;

    f32x4 acc[4][4] = {};

    for (int k0 = 0; k0 < K; k0 += 32) {
        u16x8 av0 = {}, av1 = {};
        if (agr < M) {
            av0 = *(const u16x8*)(Ap + k0);
            av1 = *(const u16x8*)(Ap + k0 + 8);
        }
        u16x8 bv0 = *(const u16x8*)(Bp + k0);
        u16x8 bv1 = *(const u16x8*)(Bp + k0 + 8);
        *(u16x8*)(As + srow * LDP + shalf) = av0;
        *(u16x8*)(As + srow * LDP + shalf + 8) = av1;
        *(u16x8*)(Bs + srow * LDP + shalf) = bv0;
        *(u16x8*)(Bs + srow * LDP + shalf + 8) = bv1;
        __syncthreads();

        bf16x8 a[4], b[4];
        #pragma unroll
        for (int m = 0; m < 4; ++m)
            a[m] = *(const bf16x8*)(As + (wr * 64 + m * 16 + l15) * LDP + lkg * 8);
        #pragma unroll
        for (int n = 0; n < 4; ++n)
            b[n] = *(const bf16x8*)(Bs + (wc * 64 + n * 16 + l15) * LDP + lkg * 8);
        #pragma unroll
        for (int m = 0; m < 4; ++m)
            #pragma unroll
            for (int n = 0; n < 4; ++n)
                acc[m][n] = __builtin_amdgcn_mfma_f32_16x16x32_bf16(a[m], b[n], acc[m][n], 0, 0, 0);
        __syncthreads();
    }

    #pragma unroll
    for (int m = 0; m < 4; ++m) {
        int rbase = br + wr * 64 + m * 16 + lkg * 4;
        #pragma unroll
        for (int n = 0; n < 4; ++n) {
            int col = bc + wc * 64 + n * 16 + l15;
            #pragma unroll
            for (int rg = 0; rg < 4; ++rg) {
                int gr = rbase + rg;
                if (gr < M) Cb[(size_t)gr * HC + col] = (__bf16)acc[m][n][rg];
            }
        }
    }
}

// ---------- merged prep: q vectors (block 16) + collapsed decoder M (blocks 0-15) ----------
__global__ void k_prep(const float* __restrict__ We1, const float* __restrict__ ae1,
                       const float* __restrict__ We2, const float* __restrict__ ae2,
                       float* __restrict__ q1, float* __restrict__ q2,
                       const float* __restrict__ Wd1, const float* __restrict__ Wd2,
                       const float* __restrict__ bd1, const float* __restrict__ bd2,
                       float* __restrict__ M, float* __restrict__ cvec) {
    if (blockIdx.x == 16) {
        int t = threadIdx.x;
        if (t >= 64) return;
        const float* We = (t < 32) ? We1 : We2;
        const float* ae = (t < 32) ? ae1 : ae2;
        float* q = (t < 32) ? q1 : q2;
        int i = t & 31, h = i >> 3, d = i & 7;
        float s = 0.f;
        for (int c = 0; c < 128; ++c) s += We[d * 512 + h * 128 + c] * ae[h * 128 + c];
        q[i] = s;
    } else {
        int tid = blockIdx.x * 256 + threadIdx.x;   // < 4096
        int i = tid >> 2, r = tid & 3;
        float s = 0.f;
        for (int k = 0; k < 256; ++k) s += Wd1[i * 256 + k] * Wd2[k * 4 + r];
        M[tid] = s;
        if (tid < 4) {
            float c = 0.f;
            for (int k = 0; k < 256; ++k) c += bd1[k] * Wd2[k * 4 + tid];
            cvec[tid] = c + bd2[tid];
        }
    }
}

// ---------- CSR build ----------
__global__ void k_count(const int* __restrict__ ei, int* __restrict__ counts) {
    int e = blockIdx.x * 256 + threadIdx.x;
    if (e >= E_TOT) return;
    int dst = (e < N_EDGES) ? ei[N_EDGES + e] : (e - N_EDGES);
    atomicAdd(counts + dst, 1);
}

__global__ __launch_bounds__(1024)
void k_scan(const int* __restrict__ counts, int* __restrict__ row_start,
            int* __restrict__ nxt) {
    __shared__ int part[1024];
    int t = threadIdx.x;
    int base = t * 20;
    int pre[20];
    int s = 0;
    #pragma unroll
    for (int i = 0; i < 20; ++i) {
        int idx = base + i;
        int c = (idx < N_NODES) ? counts[idx] : 0;
        pre[i] = s; s += c;
    }
    part[t] = s;
    __syncthreads();
    for (int off = 1; off < 1024; off <<= 1) {
        int v = (t >= off) ? part[t - off] : 0;
        __syncthreads();
        part[t] += v;
        __syncthreads();
    }
    int excl = (t == 0) ? 0 : part[t - 1];
    #pragma unroll
    for (int i = 0; i < 20; ++i) {
        int idx = base + i;
        if (idx < N_NODES) { int v = excl + pre[i]; row_start[idx] = v; nxt[idx] = v; }
    }
    if (t == 1023) row_start[N_NODES] = part[1023];
}

__global__ void k_scatter(const int* __restrict__ ei, int* __restrict__ nxt,
                          int* __restrict__ csr_src, int* __restrict__ csr_eid) {
    int e = blockIdx.x * 256 + threadIdx.x;
    if (e >= E_TOT) return;
    int src, dst;
    if (e < N_EDGES) { src = ei[e]; dst = ei[N_EDGES + e]; }
    else             { src = dst = e - N_EDGES; }
    int pos = atomicAdd(nxt + dst, 1);
    csr_src[pos] = src;
    csr_eid[pos] = e;
}

// ---------- self-loop mean edge features via CSR (no atomics) ----------
__global__ void k_mean_csr(const int* __restrict__ row_start, const int* __restrict__ csr_eid,
                           const float* __restrict__ ef, float* __restrict__ meanf) {
    int n = blockIdx.x * 32 + (threadIdx.x >> 3);
    int d = threadIdx.x & 7;
    if (n >= N_NODES) return;
    int rs = row_start[n], re = row_start[n + 1];
    float s = 0.f; int c = 0;
    for (int i = rs; i < re; ++i) {
        int eid = csr_eid[i];
        if (eid < N_EDGES) { s += ef[(size_t)eid * 8 + d]; ++c; }
    }
    meanf[n * 8 + d] = s / fmaxf((float)c, 1.f);
}

// ---------- per-node alpha_src / alpha_dst (bf16 xp) ----------
__global__ __launch_bounds__(256)
void k_node_alpha(const __bf16* __restrict__ xp, const float* __restrict__ a_s,
                  const float* __restrict__ a_d, float* __restrict__ as_out,
                  float* __restrict__ ad_out) {
    int n = blockIdx.x * 4 + (threadIdx.x >> 6);
    int lane = threadIdx.x & 63;
    if (n >= N_NODES) return;
    int h = lane >> 4;
    bf16x8 xv = *(const bf16x8*)(xp + (size_t)n * HC + lane * 8);
    const float* ap = a_s + h * C_CH + (lane & 15) * 8;
    const float* dp = a_d + h * C_CH + (lane & 15) * 8;
    float4 a0 = *(const float4*)ap, a1 = *(const float4*)(ap + 4);
    float4 d0 = *(const float4*)dp, d1 = *(const float4*)(dp + 4);
    float v[8];
    #pragma unroll
    for (int k = 0; k < 8; ++k) v[k] = (float)xv[k];
    float s = v[0] * a0.x + v[1] * a0.y + v[2] * a0.z + v[3] * a0.w +
              v[4] * a1.x + v[5] * a1.y + v[6] * a1.z + v[7] * a1.w;
    float d = v[0] * d0.x + v[1] * d0.y + v[2] * d0.z + v[3] * d0.w +
              v[4] * d1.x + v[5] * d1.y + v[6] * d1.z + v[7] * d1.w;
    #pragma unroll
    for (int off = 8; off; off >>= 1) {
        s += __shfl_xor(s, off);
        d += __shfl_xor(d, off);
    }
    if ((lane & 15) == 0) {
        as_out[n * 4 + h] = s;
        ad_out[n * 4 + h] = d;
    }
}

// ---------- alpha_e per edge ----------
__global__ void k_edge_ae(const int* __restrict__ ei, const float* __restrict__ ef,
                          const float* __restrict__ meanf, const float* __restrict__ q,
                          float* __restrict__ ae_all) {
    int e = blockIdx.x * 256 + threadIdx.x;
    if (e >= E_TOT) return;
    const float* fe = (e < N_EDGES) ? (ef + (size_t)e * 8)
                                    : (meanf + (size_t)(e - N_EDGES) * 8);
    float f[8];
    #pragma unroll
    for (int d = 0; d < 8; ++d) f[d] = fe[d];
    float4 o;
    float* op = &o.x;
    #pragma unroll
    for (int h = 0; h < 4; ++h) {
        float s = 0.f;
        #pragma unroll
        for (int d = 0; d < 8; ++d) s += f[d] * q[h * 8 + d];
        op[h] = s;
    }
    *(float4*)(ae_all + (size_t)e * 4) = o;
}

__device__ __forceinline__ void edge_alpha(int src, int eid, const float4 adn,
                                           const float* __restrict__ as_,
                                           const float* __restrict__ ae_all,
                                           float& a0, float& a1, float& a2, float& a3) {
    float4 asv = *(const float4*)(as_ + src * 4);
    float4 aev = *(const float4*)(ae_all + (size_t)eid * 4);
    a0 = asv.x + adn.x + aev.x; a0 = a0 > 0.f ? a0 : 0.2f * a0;
    a1 = asv.y + adn.y + aev.y; a1 = a1 > 0.f ? a1 : 0.2f * a1;
    a2 = asv.z + adn.z + aev.z; a2 = a2 > 0.f ? a2 : 0.2f * a2;
    a3 = asv.w + adn.w + aev.w; a3 = a3 > 0.f ? a3 : 0.2f * a3;
}

// ---------- fused per-dst: single-pass softmax + pipelined gather + ELU (+UV) ----------
template <int LAYER>
__global__ __launch_bounds__(256)
void k_dst_fused(const int* __restrict__ row_start, const int* __restrict__ csr_src,
                 const int* __restrict__ csr_eid, const __bf16* __restrict__ xp,
                 const float* __restrict__ ae_all, const float* __restrict__ as_,
                 const float* __restrict__ ad_, const float* __restrict__ b,
                 __bf16* __restrict__ zb, const float* __restrict__ Mm,
                 float* __restrict__ U, float* __restrict__ V) {
    __shared__ float4 wq[4][64];   // per-wave edge weights (4 heads)
    __shared__ int    sq[4][64];   // per-wave edge srcs
    int wv = threadIdx.x >> 6;
    int n = blockIdx.x * 4 + wv;
    int lane = threadIdx.x & 63;
    if (n >= N_NODES) return;
    int rs = row_start[n], re = row_start[n + 1];
    int cnt = re - rs;
    float4 adn = *(const float4*)(ad_ + n * 4);
    int hl = lane >> 4;

    float acc[8] = {};
    float inv;

    if (cnt <= 64) {
        // ---- fast path: alphas computed once, stashed in LDS ----
        float a0 = -1e30f, a1 = -1e30f, a2 = -1e30f, a3 = -1e30f;
        int src = 0;
        if (lane < cnt) {
            src = csr_src[rs + lane];
            edge_alpha(src, csr_eid[rs + lane], adn, as_, ae_all, a0, a1, a2, a3);
        }
        float m0 = a0, m1 = a1, m2 = a2, m3 = a3;
        #pragma unroll
        for (int off = 32; off; off >>= 1) {
            m0 = fmaxf(m0, __shfl_xor(m0, off));
            m1 = fmaxf(m1, __shfl_xor(m1, off));
            m2 = fmaxf(m2, __shfl_xor(m2, off));
            m3 = fmaxf(m3, __shfl_xor(m3, off));
        }
        float e0 = 0.f, e1 = 0.f, e2 = 0.f, e3 = 0.f;
        if (lane < cnt) {
            e0 = expf(a0 - m0); e1 = expf(a1 - m1);
            e2 = expf(a2 - m2); e3 = expf(a3 - m3);
        }
        wq[wv][lane] = make_float4(e0, e1, e2, e3);
        sq[wv][lane] = src;
        float d0 = e0, d1 = e1, d2 = e2, d3 = e3;
        #pragma unroll
        for (int off = 32; off; off >>= 1) {
            d0 += __shfl_xor(d0, off); d1 += __shfl_xor(d1, off);
            d2 += __shfl_xor(d2, off); d3 += __shfl_xor(d3, off);
        }
        float den = (hl == 0) ? d0 : (hl == 1) ? d1 : (hl == 2) ? d2 : d3;
        inv = 1.f / den;

        // pipelined gather: 8 outstanding row loads per group
        int cnt8 = (cnt + 7) & ~7;
        for (int j0 = 0; j0 < cnt8; j0 += 8) {
            bf16x8 r[8]; float w[8];
            #pragma unroll
            for (int p = 0; p < 8; ++p) {
                float4 w4 = wq[wv][j0 + p];
                int s = sq[wv][j0 + p];
                r[p] = *(const bf16x8*)(xp + (size_t)s * HC + lane * 8);
                w[p] = (hl == 0) ? w4.x : (hl == 1) ? w4.y : (hl == 2) ? w4.z : w4.w;
            }
            #pragma unroll
            for (int p = 0; p < 8; ++p)
                #pragma unroll
                for (int k = 0; k < 8; ++k) acc[k] += (float)r[p][k] * w[p];
        }
    } else {
        // ---- generic fallback (cnt > 64): two-pass with shfl broadcast ----
        float m0 = -1e30f, m1 = -1e30f, m2 = -1e30f, m3 = -1e30f;
        for (int base = rs; base < re; base += 64) {
            int i = base + lane;
            if (i < re) {
                float a0, a1, a2, a3;
                edge_alpha(csr_src[i], csr_eid[i], adn, as_, ae_all, a0, a1, a2, a3);
                m0 = fmaxf(m0, a0); m1 = fmaxf(m1, a1);
                m2 = fmaxf(m2, a2); m3 = fmaxf(m3, a3);
            }
        }
        #pragma unroll
        for (int off = 32; off; off >>= 1) {
            m0 = fmaxf(m0, __shfl_xor(m0, off));
            m1 = fmaxf(m1, __shfl_xor(m1, off));
            m2 = fmaxf(m2, __shfl_xor(m2, off));
            m3 = fmaxf(m3, __shfl_xor(m3, off));
        }
        float d0 = 0.f, d1 = 0.f, d2 = 0.f, d3 = 0.f;
        for (int base = rs; base < re; base += 64) {
            int i = base + lane;
            float e0 = 0.f, e1 = 0.f, e2 = 0.f, e3 = 0.f;
            int src = 0;
            if (i < re) {
                src = csr_src[i];
                float a0, a1, a2, a3;
                edge_alpha(src, csr_eid[i], adn, as_, ae_all, a0, a1, a2, a3);
                e0 = expf(a0 - m0); e1 = expf(a1 - m1);
                e2 = expf(a2 - m2); e3 = expf(a3 - m3);
                d0 += e0; d1 += e1; d2 += e2; d3 += e3;
            }
            int cn = min(64, re - base);
            for (int j = 0; j < cn; ++j) {
                float w0 = __shfl(e0, j), w1 = __shfl(e1, j);
                float w2 = __shfl(e2, j), w3 = __shfl(e3, j);
                int sj = __shfl(src, j);
                float w = (hl == 0) ? w0 : (hl == 1) ? w1 : (hl == 2) ? w2 : w3;
                bf16x8 xv = *(const bf16x8*)(xp + (size_t)sj * HC + lane * 8);
                #pragma unroll
                for (int k = 0; k < 8; ++k) acc[k] += (float)xv[k] * w;
            }
        }
        #pragma unroll
        for (int off = 32; off; off >>= 1) {
            d0 += __shfl_xor(d0, off); d1 += __shfl_xor(d1, off);
            d2 += __shfl_xor(d2, off); d3 += __shfl_xor(d3, off);
        }
        float den = (hl == 0) ? d0 : (hl == 1) ? d1 : (hl == 2) ? d2 : d3;
        inv = 1.f / den;
    }

    // ---- epilogue: z = elu(acc/den + b) ----
    float z[8];
    const float* bp = b + lane * 8;
    #pragma unroll
    for (int k = 0; k < 8; ++k) {
        float v = acc[k] * inv + bp[k];
        z[k] = (v > 0.f) ? v : expm1f(v);
    }

    if (LAYER == 1) {
        bf16x8 zv;
        #pragma unroll
        for (int k = 0; k < 8; ++k) zv[k] = (__bf16)z[k];
        *(bf16x8*)(zb + (size_t)n * HC + lane * 8) = zv;
    } else {
        float u[4] = {}, v[4] = {};
        #pragma unroll
        for (int k = 0; k < 8; ++k) {
            int fidx = lane * 8 + k;
            #pragma unroll
            for (int r = 0; r < 4; ++r) {
                u[r] += z[k] * Mm[fidx * 4 + r];
                v[r] += z[k] * Mm[(512 + fidx) * 4 + r];
            }
        }
        #pragma unroll
        for (int r = 0; r < 4; ++r) {
            #pragma unroll
            for (int off = 32; off; off >>= 1) {
                u[r] += __shfl_xor(u[r], off);
                v[r] += __shfl_xor(v[r], off);
            }
        }
        if (lane == 0) {
            #pragma unroll
            for (int r = 0; r < 4; ++r) { U[n * 4 + r] = u[r]; V[n * 4 + r] = v[r]; }
        }
    }
}

// ---------- per-edge output ----------
__global__ void k_edge_out(const int* __restrict__ ei, const float* __restrict__ U,
                           const float* __restrict__ V, const float* __restrict__ cvec,
                           float* __restrict__ out) {
    int idx = blockIdx.x * 256 + threadIdx.x;
    if (idx >= N_EDGES * 4) return;
    int e = idx >> 2, r = idx & 3;
    float val = U[ei[e] * 4 + r] + V[ei[N_EDGES + e] * 4 + r] + cvec[r];
    out[idx] = 1.f / (1.f + expf(-val));
}

extern "C" void kernel_launch(void* const* d_in, const int* in_sizes, int n_in,
                              void* d_out, int out_size, void* d_ws, size_t ws_size,
                              hipStream_t stream) {
    (void)in_sizes; (void)n_in; (void)out_size; (void)ws_size;
    const float* x      = (const float*)d_in[0];
    const int*   ei     = (const int*)d_in[1];
    const float* ef     = (const float*)d_in[2];
    const float* W1     = (const float*)d_in[3];
    const float* a_src1 = (const float*)d_in[4];
    const float* a_dst1 = (const float*)d_in[5];
    const float* We1    = (const float*)d_in[6];
    const float* a_e1   = (const float*)d_in[7];
    const float* b1     = (const float*)d_in[8];
    const float* W2     = (const float*)d_in[9];
    const float* a_src2 = (const float*)d_in[10];
    const float* a_dst2 = (const float*)d_in[11];
    const float* We2    = (const float*)d_in[12];
    const float* a_e2   = (const float*)d_in[13];
    const float* b2     = (const float*)d_in[14];
    const float* Wd1    = (const float*)d_in[15];
    const float* bd1    = (const float*)d_in[16];
    const float* Wd2    = (const float*)d_in[17];
    const float* bd2    = (const float*)d_in[18];
    float* out = (float*)d_out;

    // workspace layout
    float* ae_all = (float*)d_ws;                            // E_TOT*4
    float* as_    = ae_all + (size_t)E_TOT * 4;              // N*4
    float* ad_    = as_ + N_NODES * 4;                       // N*4
    float* meanf  = ad_ + N_NODES * 4;                       // N*8
    float* q1     = meanf + N_NODES * 8;                     // 32
    float* q2     = q1 + 32;                                 // 32
    float* Mm     = q2 + 32;                                 // 4096
    float* cv     = Mm + 4096;                               // 4
    float* U      = cv + 4;                                  // N*4
    float* V      = U + N_NODES * 4;                         // N*4
    int* row_start = (int*)(V + N_NODES * 4);                // 20004
    int* counts    = row_start + 20004;                      // N
    int* nxt       = counts + N_NODES;                       // N
    int* csr_src   = nxt + N_NODES;                          // E_TOT
    int* csr_eid   = csr_src + E_TOT;                        // E_TOT
    __bf16* xb   = (__bf16*)(csr_eid + E_TOT);               // N*64
    __bf16* Ab   = xb + (size_t)N_NODES * FIN;               // N*512 (xp current layer)
    __bf16* z1b  = Ab + (size_t)N_NODES * HC;                // N*512
    __bf16* Wt1  = z1b + (size_t)N_NODES * HC;               // 512*64
    __bf16* Wt2  = Wt1 + HC * FIN;                           // 512*512

    // ---- prep ----
    hipMemsetAsync(counts, 0, N_NODES * sizeof(int), stream);
    k_count<<<(E_TOT + 255) / 256, 256, 0, stream>>>(ei, counts);
    k_scan<<<1, 1024, 0, stream>>>(counts, row_start, nxt);
    k_scatter<<<(E_TOT + 255) / 256, 256, 0, stream>>>(ei, nxt, csr_src, csr_eid);
    k_mean_csr<<<(N_NODES + 31) / 32, 256, 0, stream>>>(row_start, csr_eid, ef, meanf);
    k_prep<<<17, 256, 0, stream>>>(We1, a_e1, We2, a_e2, q1, q2, Wd1, Wd2, bd1, bd2, Mm, cv);
    k_cvt<<<(NX4 + W1T + W2T + 255) / 256, 256, 0, stream>>>(x, xb, W1, Wt1, W2, Wt2);

    const int nwg = ((N_NODES + 127) / 128) * 4;   // 628

    // ---- layer 1 ----
    k_gemm_bf16<<<nwg, 256, 0, stream>>>(xb, Wt1, Ab, N_NODES, FIN);
    k_node_alpha<<<(N_NODES + 3) / 4, 256, 0, stream>>>(Ab, a_src1, a_dst1, as_, ad_);
    k_edge_ae<<<(E_TOT + 255) / 256, 256, 0, stream>>>(ei, ef, meanf, q1, ae_all);
    k_dst_fused<1><<<(N_NODES + 3) / 4, 256, 0, stream>>>(
        row_start, csr_src, csr_eid, Ab, ae_all, as_, ad_, b1, z1b, nullptr, nullptr, nullptr);

    // ---- layer 2 ----
    k_gemm_bf16<<<nwg, 256, 0, stream>>>(z1b, Wt2, Ab, N_NODES, HC);
    k_node_alpha<<<(N_NODES + 3) / 4, 256, 0, stream>>>(Ab, a_src2, a_dst2, as_, ad_);
    k_edge_ae<<<(E_TOT + 255) / 256, 256, 0, stream>>>(ei, ef, meanf, q2, ae_all);
    k_dst_fused<2><<<(N_NODES + 3) / 4, 256, 0, stream>>>(
        row_start, csr_src, csr_eid, Ab, ae_all, as_, ad_, b2, nullptr, Mm, U, V);

    // ---- output ----
    k_edge_out<<<(N_EDGES * 4 + 255) / 256, 256, 0, stream>>>(ei, U, V, cv, out);
}